// Round 10
// baseline (615.056 us; speedup 1.0000x reference)
//
#include <hip/hip_runtime.h>
#include <hip/hip_bf16.h>

typedef unsigned short u16;
typedef __attribute__((ext_vector_type(8))) short short8;   // 8 bf16 (4 VGPRs)
typedef __attribute__((ext_vector_type(4))) float f32x4;

#define ND 30000
#define NP 30000
#define NS 10000
#define CSTRIDE 30016          // offsets per-relation stride (ints)
#define ETOT 4500000
#define CHUNK 9216             // edges per chunk (36 per thread)
#define NC 489                 // ceil(ETOT/CHUNK)
#define NBR 118                // buckets per relation (256 dsts each)
#define NB 590                 // total buckets

__device__ __forceinline__ float bf2f(u16 u) {
  union { unsigned int i; float f; } c; c.i = ((unsigned int)u) << 16; return c.f;
}
__device__ __forceinline__ u16 f2bf(float f) {
  union { float f; unsigned int i; } c; c.f = f;
  unsigned int u = c.i;
  unsigned int r = (u + 0x7fffu + ((u >> 16) & 1u)) >> 16;
  return (u16)r;
}

// Block-parallel input dtype detect (256 threads, ~1 us): for fp32 data the
// sampled u16s are mantissa halves (~16% sane exponent); bf16 ~100%.
__device__ __forceinline__ int detect_isbf(const void* x) {
  __shared__ int cnt4[4];
  const int tid = threadIdx.x;
  const u16 v = ((const u16*)x)[2 * tid];
  const int e = (v >> 7) & 0xff;
  const unsigned long long m = __ballot(e >= 100 && e <= 140);
  if ((tid & 63) == 0) cnt4[tid >> 6] = __popcll(m);
  __syncthreads();
  const int sane = cnt4[0] + cnt4[1] + cnt4[2] + cnt4[3];
  return sane >= 200;
}

__device__ __forceinline__ float ld_in(const void* p, int i, int isbf) {
  return isbf ? bf2f(((const u16*)p)[i]) : ((const float*)p)[i];
}

// ---------------------------------------------------------------------------
// Edge job tables
// ---------------------------------------------------------------------------
struct EJobs { const int* src[5]; const int* dst[5]; };
__device__ __forceinline__ int e_job(int e) {
  return (e >= 1000000) + (e >= 2000000) + (e >= 2500000) + (e >= 3500000);
}
__device__ __forceinline__ int e_base(int j) {
  const int base[6] = {0, 1000000, 2000000, 2500000, 3500000, 4500000};
  return base[j];
}

// ---------------------------------------------------------------------------
// prep: Wal[h][k] = sum_d W[k][h*16+d]*al[h*16+d] (and War with ar)
// ---------------------------------------------------------------------------
struct PJobs { const void* W[5]; const void* al[5]; const void* ar[5];
               float* wal[5]; float* war[5]; };
__device__ void prep_dev(const PJobs& J, int b, int isbf) {
  const int tid = threadIdx.x;
  if (tid >= 128) return;
  const int k = tid;
  for (int h = 0; h < 8; ++h) {
    float sa = 0.f, sr = 0.f;
    for (int d = 0; d < 16; ++d) {
      const float wv = ld_in(J.W[b], k * 128 + h * 16 + d, isbf);
      sa = fmaf(wv, ld_in(J.al[b], h * 16 + d, isbf), sa);
      sr = fmaf(wv, ld_in(J.ar[b], h * 16 + d, isbf), sr);
    }
    J.wal[b][h * 128 + k] = sa;
    J.war[b][h * 128 + k] = sr;
  }
}

// ---------------------------------------------------------------------------
// hist: per-chunk bucket histogram (LDS atomics only)
// ---------------------------------------------------------------------------
__device__ void hist_dev(const EJobs& J, int* __restrict__ ghist, int c) {
  __shared__ int hsh[NB];
  const int tid = threadIdx.x;
  for (int i = tid; i < NB; i += 256) hsh[i] = 0;
  __syncthreads();
  const int e0 = c * CHUNK;
  #pragma unroll 4
  for (int t = 0; t < 36; ++t) {
    const int e = e0 + t * 256 + tid;
    if (e < ETOT) {
      const int j = e_job(e);
      const int d = J.dst[j][e - e_base(j)];
      atomicAdd(&hsh[j * NBR + (d >> 8)], 1);
    }
  }
  __syncthreads();
  for (int i = tid; i < NB; i += 256) ghist[c * NB + i] = hsh[i];
}

// k_front: blocks 0..4 = prep, 5.. = hist
__global__ __launch_bounds__(256) void k_front(PJobs PJ, EJobs EJ,
    const void* xdet, int* __restrict__ ghist) {
  if (blockIdx.x < 5) {
    const int isbf = detect_isbf(xdet);
    prep_dev(PJ, blockIdx.x, isbf);
  } else {
    hist_dev(EJ, ghist, blockIdx.x - 5);
  }
}

// ---------------------------------------------------------------------------
// pack: B matrices into MFMA fragment order (jobs 0..4 = W|Wal|War, 5 = W1)
// ---------------------------------------------------------------------------
struct KPack { const void* W[6]; const float* wal[6]; const float* war[6];
               u16* out[6]; };
__device__ void pack_dev(const KPack& J, int b, int isbf) {
  const int job = b / 9;
  const int i0 = (b % 9) * 2048 + threadIdx.x * 8;
  const int kc = i0 / 4608;
  const int rem = i0 - kc * 4608;
  const int n = rem >> 5;
  const int q = (rem >> 3) & 3;
  u16 vals[8];
  #pragma unroll
  for (int j = 0; j < 8; ++j) {
    const int k = kc * 32 + q * 8 + j;
    float v;
    if (job == 5)      v = (n < 128) ? ld_in(J.W[5], k * 128 + n, isbf) : 0.f;
    else if (n < 128)  v = ld_in(J.W[job], k * 128 + n, isbf);
    else if (n < 136)  v = J.wal[job][(n - 128) * 128 + k];
    else               v = J.war[job][(n - 136) * 128 + k];
    vals[j] = f2bf(v);
  }
  *(uint4*)&J.out[job][i0] = *(uint4*)vals;
}

// bucketscan: per bucket, prefix over chunks
__device__ void bucketscan_dev(const int* __restrict__ ghist,
    int* __restrict__ gcur, int* __restrict__ totals, int b) {
  __shared__ int ts[256];
  const int tid = threadIdx.x;
  int v0 = 0, v1 = 0;
  const int c0 = tid * 2;
  if (c0 < NC) v0 = ghist[c0 * NB + b];
  if (c0 + 1 < NC) v1 = ghist[(c0 + 1) * NB + b];
  ts[tid] = v0 + v1;
  __syncthreads();
  for (int o = 1; o < 256; o <<= 1) {
    const int x = (tid >= o) ? ts[tid - o] : 0;
    __syncthreads();
    ts[tid] += x;
    __syncthreads();
  }
  int run = (tid == 0) ? 0 : ts[tid - 1];
  if (c0 < NC) { gcur[b * NC + c0] = run; run += v0; }
  if (c0 + 1 < NC) gcur[b * NC + c0 + 1] = run;
  if (tid == 255) totals[b] = ts[255];
}

// k_mid: blocks 0..53 = pack, 54.. = bucketscan
__global__ __launch_bounds__(256) void k_mid(KPack KJ, const void* xdet,
    const int* __restrict__ ghist, int* __restrict__ gcur, int* __restrict__ totals) {
  if (blockIdx.x < 54) {
    const int isbf = detect_isbf(xdet);
    pack_dev(KJ, blockIdx.x, isbf);
  } else {
    bucketscan_dev(ghist, gcur, totals, blockIdx.x - 54);
  }
}

// ---------------------------------------------------------------------------
// base prefix over the 590 bucket totals, recomputed in LDS (tiny)
// ---------------------------------------------------------------------------
__device__ void base_from_totals(const int* __restrict__ totals, int* bsh) {
  __shared__ int ts[256];
  const int tid = threadIdx.x;
  const int i0 = tid * 3;
  int v0 = 0, v1 = 0, v2 = 0;
  if (i0 < NB) v0 = totals[i0];
  if (i0 + 1 < NB) v1 = totals[i0 + 1];
  if (i0 + 2 < NB) v2 = totals[i0 + 2];
  ts[tid] = v0 + v1 + v2;
  __syncthreads();
  for (int o = 1; o < 256; o <<= 1) {
    const int x = (tid >= o) ? ts[tid - o] : 0;
    __syncthreads();
    ts[tid] += x;
    __syncthreads();
  }
  int run = (tid == 0) ? 0 : ts[tid - 1];
  if (i0 < NB) { bsh[i0] = run; run += v0; }
  if (i0 + 1 < NB) { bsh[i0 + 1] = run; run += v1; }
  if (i0 + 2 < NB) bsh[i0 + 2] = run;
  if (tid == 0) bsh[NB] = ETOT;
  __syncthreads();
}

// ---------------------------------------------------------------------------
// bin: scatter (dst&255 | src) into bucket-ordered runs (LDS cursors)
// ---------------------------------------------------------------------------
__global__ __launch_bounds__(256) void k_bin(EJobs J,
    const int* __restrict__ gcur, const int* __restrict__ totals,
    unsigned int* __restrict__ bin) {
  __shared__ int bsh[NB + 1];
  __shared__ int cur[NB];
  base_from_totals(totals, bsh);
  const int c = blockIdx.x, tid = threadIdx.x;
  for (int i = tid; i < NB; i += 256) cur[i] = bsh[i] + gcur[i * NC + c];
  __syncthreads();
  const int e0 = c * CHUNK;
  #pragma unroll 4
  for (int t = 0; t < 36; ++t) {
    const int e = e0 + t * 256 + tid;
    if (e < ETOT) {
      const int j = e_job(e);
      const int le = e - e_base(j);
      const int d = J.dst[j][le];
      const int s = J.src[j][le];
      const int pos = atomicAdd(&cur[j * NBR + (d >> 8)], 1);
      bin[pos] = ((unsigned int)(d & 255) << 16) | (unsigned int)s;
    }
  }
}

// ---------------------------------------------------------------------------
// fill2: per bucket, sort 256 dsts in LDS, emit u16 CSR + offsets
// ---------------------------------------------------------------------------
__device__ void fill2_dev(const unsigned int* __restrict__ bin,
    const int* __restrict__ totals, u16* __restrict__ csr,
    int* __restrict__ offsets, int b) {
  __shared__ int bsh2[NB + 1];
  __shared__ int cnt[256], curs[256];
  base_from_totals(totals, bsh2);
  const int tid = threadIdx.x;
  const int rel = b / NBR;
  const int bloc = b - rel * NBR;
  const int d0 = bloc << 8;
  const int gbeg = bsh2[b];
  const int n = bsh2[b + 1] - gbeg;
  cnt[tid] = 0;
  __syncthreads();
  for (int i = tid; i < n; i += 256)
    atomicAdd(&cnt[bin[gbeg + i] >> 16], 1);
  __syncthreads();
  const int orig = cnt[tid];
  for (int o = 1; o < 256; o <<= 1) {
    const int x = (tid >= o) ? cnt[tid - o] : 0;
    __syncthreads();
    cnt[tid] += x;
    __syncthreads();
  }
  const int ex = cnt[tid] - orig;
  curs[tid] = ex;
  const int ebr = e_base(rel);
  const int d = d0 + tid;
  if (d < 30000) offsets[rel * CSTRIDE + d] = (gbeg - ebr) + ex;
  if (bloc == NBR - 1 && tid == 0)
    offsets[rel * CSTRIDE + 30000] = e_base(rel + 1) - ebr;
  __syncthreads();
  for (int i = tid; i < n; i += 256) {
    const unsigned int v = bin[gbeg + i];
    const int pos = atomicAdd(&curs[v >> 16], 1);
    csr[gbeg + pos] = (u16)(v & 0xffffu);
  }
}

// ---------------------------------------------------------------------------
// MFMA transform (R6-proven): [Nx128]@[128x144]; tiles 0..7->z, 8->el/er.
// z now stored split by dim-half: z[(t>>2)*N*64 + row*64 + (t&3)*16 + c]
// so each 64-dim half is a contiguous 3.84MB (L2-resident) table.
// ---------------------------------------------------------------------------
struct XJobs {
  const void* x[8]; const u16* bp[8]; u16* z[8]; float* el[8]; float* er[8];
  int N[8]; int t0[8]; int blk0[9];
};
__device__ void xform_dev(const XJobs& J, int xb, int isbf) {
  __shared__ __align__(16) u16 Bf[18432];
  __shared__ __align__(16) u16 As[64 * 136];
  const int tid = threadIdx.x;
  int job = 0;
  while (xb >= J.blk0[job + 1]) ++job;
  const int row0 = (xb - J.blk0[job]) * 64;
  const int N = J.N[job];
  const int t0 = J.t0[job];
  const u16* bp = J.bp[job];
  const void* x = J.x[job];

  if (t0 == 0) {
    for (int i = tid * 8; i < 18432; i += 2048)
      *(uint4*)&Bf[i] = *(const uint4*)&bp[i];
  } else {
    const int i = tid * 8;
    const int kc = i >> 9;
    const int off = (kc * 144 + 128) * 32 + (i & 511);
    *(uint4*)&Bf[off] = *(const uint4*)&bp[off];
  }

  if (isbf) {
    const uint4* xv = (const uint4*)x;
    for (int i = tid; i < 1024; i += 256) {
      const int r = i >> 4, c8 = i & 15;
      const int row = row0 + r;
      uint4 v = make_uint4(0, 0, 0, 0);
      if (row < N) v = xv[row * 16 + c8];
      *(uint4*)&As[r * 136 + c8 * 8] = v;
    }
  } else {
    const float4* xf = (const float4*)x;
    for (int i = tid; i < 2048; i += 256) {
      const int r = i >> 5, c4 = i & 31;
      const int row = row0 + r;
      unsigned long long pkv = 0ull;
      if (row < N) {
        const float4 v = xf[row * 32 + c4];
        pkv = (unsigned long long)f2bf(v.x) | ((unsigned long long)f2bf(v.y) << 16)
            | ((unsigned long long)f2bf(v.z) << 32) | ((unsigned long long)f2bf(v.w) << 48);
      }
      *(unsigned long long*)&As[r * 136 + c4 * 4] = pkv;
    }
  }
  __syncthreads();

  const int wave = tid >> 6;
  const int lane = tid & 63;
  const int q = lane >> 4;
  const int c = lane & 15;

  f32x4 accT[8];
  f32x4 acc8 = (f32x4){0.f, 0.f, 0.f, 0.f};
  if (t0 == 0) {
    #pragma unroll
    for (int t = 0; t < 8; ++t) accT[t] = (f32x4){0.f, 0.f, 0.f, 0.f};
  }

  #pragma unroll
  for (int kc = 0; kc < 4; ++kc) {
    const short8 a = *(const short8*)&As[(wave * 16 + c) * 136 + kc * 32 + q * 8];
    if (t0 == 0) {
      #pragma unroll
      for (int t = 0; t < 8; ++t) {
        const short8 bb = *(const short8*)&Bf[((kc * 144 + t * 16 + c) * 4 + q) * 8];
        accT[t] = __builtin_amdgcn_mfma_f32_16x16x32_bf16(a, bb, accT[t], 0, 0, 0);
      }
    }
    const short8 b8 = *(const short8*)&Bf[((kc * 144 + 128 + c) * 4 + q) * 8];
    acc8 = __builtin_amdgcn_mfma_f32_16x16x32_bf16(a, b8, acc8, 0, 0, 0);
  }

  const int rbase = row0 + wave * 16 + q * 4;
  if (t0 == 0 && J.z[job]) {
    u16* zo = J.z[job];
    #pragma unroll
    for (int t = 0; t < 8; ++t) {
      u16* zh = zo + (t >> 2) * N * 64;
      #pragma unroll
      for (int r = 0; r < 4; ++r) {
        const int row = rbase + r;
        if (row < N) zh[row * 64 + (t & 3) * 16 + c] = f2bf(accT[t][r]);
      }
    }
  }
  #pragma unroll
  for (int r = 0; r < 4; ++r) {
    const int row = rbase + r;
    if (row < N) {
      const float v = acc8[r];
      if (c < 8) { if (J.el[job]) J.el[job][row * 8 + c] = v; }
      else       { if (J.er[job]) J.er[job][row * 8 + (c - 8)] = v; }
    }
  }
}

// k_l4: blocks 0..589 = fill2, 590.. = xform
__global__ __launch_bounds__(256) void k_l4(XJobs XJ, const void* xdet,
    const unsigned int* __restrict__ bin, const int* __restrict__ totals,
    u16* __restrict__ csr, int* __restrict__ offsets) {
  if (blockIdx.x < NB) {
    fill2_dev(bin, totals, csr, offsets, blockIdx.x);
  } else {
    const int isbf = detect_isbf(xdet);
    xform_dev(XJ, blockIdx.x - NB, isbf);
  }
}

// ---------------------------------------------------------------------------
// Aggregation, two dim-half passes (heads 0-3 / 4-7). Per pass the z half
// table is 3.84MB -> per-XCD L2 resident. Wave split: lanes 0-31 process
// edges p..p+7, lanes 32-63 p+8..p+15 (each half covers 64 dims at 2/lane);
// halves merged via shfl_xor(32). Exp work is NOT duplicated (4 heads/pass).
// ---------------------------------------------------------------------------
struct AJobs { const u16* csr[5]; const int* off[5]; const float* el[5];
               const float* er[5]; const u16* z[5]; const void* b[5];
               u16* feats[5]; int stride[5]; int nsrc[5]; };
__global__ __launch_bounds__(256) void k_agg_all(AJobs J, const void* xdet) {
  const int isbf = detect_isbf(xdet);
  const int gw = (blockIdx.x * 256 + threadIdx.x) >> 6;   // 0..299999
  const int lane = threadIdx.x & 63;
  const int pass = (gw >= 150000) ? 1 : 0;
  const int rw = gw - pass * 150000;
  const int job = rw / 30000;
  const int d = rw - job * 30000;
  const int dim2 = lane & 31;         // dim pair within 64-dim half
  const int hx = (lane >> 3) & 3;     // head (relative to pass), both duties
  const int eidx = ((lane & 32) >> 2) + (lane & 7);  // exp duty: edge in window
  const float* el = J.el[job];
  const u16* zh = J.z[job] + pass * J.nsrc[job] * 64;
  const u16* csr = J.csr[job];
  const float erh = J.er[job][d * 8 + pass * 4 + hx];
  const int beg = J.off[job][d];
  const int end = J.off[job][d + 1];
  const int exbase = ((lane & 32) << 2) + hx * 32;  // bpermute base for ex
  const int srcbase = lane & 32;                    // bpermute base for src

  float a0 = 0.f, a1 = 0.f, denP = 0.f;
  for (int p = beg; p < end; p += 16) {
    const int ci = p + (lane & 15);
    const int sE = (int)csr[ci < end ? ci : end - 1];
    // exp duty: edge eidx of window, head hx of this pass
    const int sx = __builtin_amdgcn_ds_bpermute(4 * eidx, sE);
    float eh = el[sx * 8 + pass * 4 + hx] + erh;
    eh = fminf(fmaxf(eh, 0.2f * eh), 60.f);
    const float exE = (p + eidx < end) ? __expf(eh) : 0.f;
    denP += exE;
    const int exb = __float_as_int(exE);
    int sj[8];
    #pragma unroll
    for (int j = 0; j < 8; ++j)
      sj[j] = __builtin_amdgcn_ds_bpermute(srcbase + 4 * j, sE);
    unsigned int zp[8];
    #pragma unroll
    for (int j = 0; j < 8; ++j)
      zp[j] = *(const unsigned int*)(zh + sj[j] * 64 + dim2 * 2);
    float exi[8];
    #pragma unroll
    for (int j = 0; j < 8; ++j)
      exi[j] = __int_as_float(__builtin_amdgcn_ds_bpermute(exbase + 4 * j, exb));
    #pragma unroll
    for (int j = 0; j < 8; ++j) {
      union { unsigned int u; float f; } lo, hi;
      lo.u = zp[j] << 16; hi.u = zp[j] & 0xffff0000u;
      a0 = fmaf(exi[j], lo.f, a0);
      a1 = fmaf(exi[j], hi.f, a1);
    }
  }
  denP += __shfl_xor(denP, 1);
  denP += __shfl_xor(denP, 2);
  denP += __shfl_xor(denP, 4);        // sum over i8 within (half, head)
  denP += __shfl_xor(denP, 32);       // add other half's edges
  a0 += __shfl_xor(a0, 32);
  a1 += __shfl_xor(a1, 32);
  if (lane < 32) {
    const float inv = 1.f / fmaxf(denP, 1e-9f);
    const int j0 = pass * 64 + dim2 * 2;
    const float v0 = a0 * inv + ld_in(J.b[job], j0, isbf);
    const float v1 = a1 * inv + ld_in(J.b[job], j0 + 1, isbf);
    const unsigned int packed = (unsigned int)f2bf(v0) | ((unsigned int)f2bf(v1) << 16);
    *(unsigned int*)(J.feats[job] + d * J.stride[job] + j0) = packed;
  }
}

// ---------------------------------------------------------------------------
// MFMA semantic score (R6-proven) + inline detect
// ---------------------------------------------------------------------------
__global__ __launch_bounds__(256) void k_sem_all(
    const u16* __restrict__ f, const u16* __restrict__ w1pack,
    const void* __restrict__ b1, const void* __restrict__ W2,
    const void* __restrict__ b2, float* __restrict__ s_out, int total,
    const void* xdet)
{
  __shared__ __align__(16) u16 Bf[18432];
  __shared__ __align__(16) u16 As[64 * 136];
  __shared__ float b1S[128], W2S[128];
  const int isbf = detect_isbf(xdet);
  const int tid = threadIdx.x;
  const int row0 = blockIdx.x * 64;

  for (int i = tid * 8; i < 18432; i += 2048)
    *(uint4*)&Bf[i] = *(const uint4*)&w1pack[i];
  if (tid < 128) { b1S[tid] = ld_in(b1, tid, isbf); W2S[tid] = ld_in(W2, tid, isbf); }
  {
    const uint4* xv = (const uint4*)f;
    for (int i = tid; i < 1024; i += 256) {
      const int r = i >> 4, c8 = i & 15;
      const int row = row0 + r;
      uint4 v = make_uint4(0, 0, 0, 0);
      if (row < total) v = xv[row * 16 + c8];
      *(uint4*)&As[r * 136 + c8 * 8] = v;
    }
  }
  __syncthreads();

  const int wave = tid >> 6;
  const int lane = tid & 63;
  const int q = lane >> 4;
  const int c = lane & 15;

  f32x4 acc[8];
  #pragma unroll
  for (int t = 0; t < 8; ++t) acc[t] = (f32x4){0.f, 0.f, 0.f, 0.f};

  #pragma unroll
  for (int kc = 0; kc < 4; ++kc) {
    const short8 a = *(const short8*)&As[(wave * 16 + c) * 136 + kc * 32 + q * 8];
    #pragma unroll
    for (int t = 0; t < 8; ++t) {
      const short8 bb = *(const short8*)&Bf[((kc * 144 + t * 16 + c) * 4 + q) * 8];
      acc[t] = __builtin_amdgcn_mfma_f32_16x16x32_bf16(a, bb, acc[t], 0, 0, 0);
    }
  }

  float part[4] = {0.f, 0.f, 0.f, 0.f};
  #pragma unroll
  for (int t = 0; t < 8; ++t) {
    const int n = t * 16 + c;
    const float b1v = b1S[n];
    const float w2v = W2S[n];
    #pragma unroll
    for (int r = 0; r < 4; ++r) {
      const float hv = acc[t][r] + b1v;
      const float e = __expf(2.f * hv);
      const float th = 1.f - 2.f / (e + 1.f);
      part[r] = fmaf(th, w2v, part[r]);
    }
  }
  #pragma unroll
  for (int r = 0; r < 4; ++r) {
    part[r] += __shfl_xor(part[r], 1);
    part[r] += __shfl_xor(part[r], 2);
    part[r] += __shfl_xor(part[r], 4);
    part[r] += __shfl_xor(part[r], 8);
  }
  if (c == 0) {
    const float b2v = ld_in(b2, 0, isbf);
    #pragma unroll
    for (int r = 0; r < 4; ++r) {
      const int row = row0 + wave * 16 + q * 4 + r;
      if (row < total) s_out[row] = part[r] + b2v;
    }
  }
}

// ---------------------------------------------------------------------------
// Combine: 2 dims per thread (u32 feat loads), softmax over R scores.
// ---------------------------------------------------------------------------
__global__ __launch_bounds__(256) void k_combine_all(
    const u16* __restrict__ feats, const float* __restrict__ s,
    void* __restrict__ out, const void* xdet)
{
  const int isbf = detect_isbf(xdet);
  const int i = blockIdx.x * 256 + threadIdx.x;   // u32-pair index
  if (i >= 3840000) return;
  const bool drug = (i < 1920000);
  const int li = drug ? i : i - 1920000;
  const int n = li >> 6;          // 64 u32 per 128-dim row
  const int j2 = li & 63;
  const float* sr = s + (drug ? n * 3 : 90000 + n * 2);
  const u16* fb = feats + (drug ? n * 384 : 11520000 + n * 256) + j2 * 2;
  const float s0v = sr[0];
  const float s1v = sr[1];
  const float s2v = drug ? sr[2] : -3.4e38f;
  const float m = fmaxf(fmaxf(s0v, s1v), s2v);
  const float w0 = __expf(s0v - m);
  const float w1 = __expf(s1v - m);
  const float w2 = drug ? __expf(s2v - m) : 0.f;
  const float inv = 1.f / (w0 + w1 + w2);
  const unsigned int f0 = *(const unsigned int*)(fb);
  const unsigned int f1 = *(const unsigned int*)(fb + 128);
  union { unsigned int u; float f; } t;
  float acc0, acc1;
  t.u = f0 << 16;          acc0 = w0 * t.f;
  t.u = f0 & 0xffff0000u;  acc1 = w0 * t.f;
  t.u = f1 << 16;          acc0 = fmaf(w1, t.f, acc0);
  t.u = f1 & 0xffff0000u;  acc1 = fmaf(w1, t.f, acc1);
  if (drug) {
    const unsigned int f2 = *(const unsigned int*)(fb + 256);
    t.u = f2 << 16;          acc0 = fmaf(w2, t.f, acc0);
    t.u = f2 & 0xffff0000u;  acc1 = fmaf(w2, t.f, acc1);
  }
  acc0 *= inv; acc1 *= inv;
  if (isbf) {
    const unsigned int packed = (unsigned int)f2bf(acc0) | ((unsigned int)f2bf(acc1) << 16);
    ((unsigned int*)out)[i] = packed;
  } else {
    float2 v; v.x = acc0; v.y = acc1;
    ((float2*)out)[i] = v;
  }
}

extern "C" void kernel_launch(void* const* d_in, const int* in_sizes, int n_in,
                              void* d_out, int out_size, void* d_ws, size_t ws_size,
                              hipStream_t stream)
{
  (void)in_sizes; (void)n_in; (void)out_size; (void)ws_size;

  const void* h_drug = d_in[0];
  const void* h_prot = d_in[1];
  const void* h_se   = d_in[2];
  const void* W_dd = d_in[3];  const void* al_dd = d_in[4];
  const void* ar_dd = d_in[5]; const void* b_dd  = d_in[6];
  const void* W_dp = d_in[7];  const void* al_dp = d_in[8];
  const void* ar_dp = d_in[9]; const void* b_dp  = d_in[10];
  const void* W_pd = d_in[11]; const void* al_pd = d_in[12];
  const void* ar_pd = d_in[13];const void* b_pd  = d_in[14];
  const void* W_pp = d_in[15]; const void* al_pp = d_in[16];
  const void* ar_pp = d_in[17];const void* b_pp  = d_in[18];
  const void* W_sd = d_in[19]; const void* al_sd = d_in[20];
  const void* ar_sd = d_in[21];const void* b_sd  = d_in[22];
  const void* W1 = d_in[23];   const void* b1 = d_in[24];
  const void* W2 = d_in[25];   const void* b2 = d_in[26];
  const int* src_dd = (const int*)d_in[27];
  const int* dst_dd = (const int*)d_in[28];
  const int* src_dp = (const int*)d_in[29];
  const int* dst_dp = (const int*)d_in[30];
  const int* src_pd = (const int*)d_in[31];
  const int* dst_pd = (const int*)d_in[32];
  const int* src_pp = (const int*)d_in[33];
  const int* dst_pp = (const int*)d_in[34];
  const int* src_sd = (const int*)d_in[35];
  const int* dst_sd = (const int*)d_in[36];

  // ---- workspace layout (~94.1 MB <= 101.4 MB proven in R6) ----
  char* w = (char*)d_ws;
  float* el5   = (float*)(w);                    // 4,800,000
  float* er5   = (float*)(w + 4800000);          // 4,800,000
  u16* z_dd    = (u16*)(w + 9600000);            // 7,680,000 (2 halves)
  u16* z_pd    = (u16*)(w + 17280000);           // 7,680,000
  u16* z_sd    = (u16*)(w + 24960000);           // 2,560,000
  u16* z_dp    = (u16*)(w + 27520000);           // 7,680,000
  u16* z_pp    = (u16*)(w + 35200000);           // 7,680,000
  int* offsets = (int*)(w + 42880000);           // 600,320
  u16* csr     = (u16*)(w + 43480320);           // 9,000,000
  int* ghist   = (int*)(w + 52480320);           // 1,154,040
  int* gcur    = (int*)(w + 53634560);           // 1,154,040
  int* totals  = (int*)(w + 54788608);           // 2,360
  float* s     = (float*)(w + 54791168);         // 600,000
  u16* feats   = (u16*)(w + 55391232);           // 38,400,000 (16B aligned)
  unsigned int* bin = (unsigned int*)(w + 55391232); // aliases feats (dead before agg)
  float* ww    = (float*)(w + 93791232);         // 40,960 (wal/war x5)
  u16* packs   = (u16*)(w + 93832192);           // 221,184 -> end 94,053,376

  float *wal[5], *war[5];
  for (int r = 0; r < 5; ++r) { wal[r] = ww + r * 2048; war[r] = ww + r * 2048 + 1024; }
  u16* pk[6];
  for (int r = 0; r < 6; ++r) pk[r] = packs + r * 18432;
  float* el_r[5]; float* er_r[5];
  for (int r = 0; r < 5; ++r) { el_r[r] = el5 + r * 240000; er_r[r] = er5 + r * 240000; }
  u16* feats_d = feats;               // drug: 30000 x 384
  u16* feats_p = feats + 11520000;    // prot: 30000 x 256

  const dim3 blk(256);

  // rel order: 0=dd 1=pd 2=sd 3=dp 4=pp
  PJobs pj;
  pj.W[0]=W_dd; pj.al[0]=al_dd; pj.ar[0]=ar_dd;
  pj.W[1]=W_pd; pj.al[1]=al_pd; pj.ar[1]=ar_pd;
  pj.W[2]=W_sd; pj.al[2]=al_sd; pj.ar[2]=ar_sd;
  pj.W[3]=W_dp; pj.al[3]=al_dp; pj.ar[3]=ar_dp;
  pj.W[4]=W_pp; pj.al[4]=al_pp; pj.ar[4]=ar_pp;
  for (int r = 0; r < 5; ++r) { pj.wal[r] = wal[r]; pj.war[r] = war[r]; }

  EJobs ej;
  ej.src[0]=src_dd; ej.dst[0]=dst_dd;
  ej.src[1]=src_pd; ej.dst[1]=dst_pd;
  ej.src[2]=src_sd; ej.dst[2]=dst_sd;
  ej.src[3]=src_dp; ej.dst[3]=dst_dp;
  ej.src[4]=src_pp; ej.dst[4]=dst_pp;

  KPack kp;
  kp.W[0]=W_dd; kp.W[1]=W_pd; kp.W[2]=W_sd; kp.W[3]=W_dp; kp.W[4]=W_pp; kp.W[5]=W1;
  for (int r = 0; r < 5; ++r) { kp.wal[r] = wal[r]; kp.war[r] = war[r]; }
  kp.wal[5]=nullptr; kp.war[5]=nullptr;
  for (int r = 0; r < 6; ++r) kp.out[r] = pk[r];

  XJobs xj;
  auto setx = [&](int i, const void* x, const u16* bp, u16* z, float* el,
                  float* er, int N, int t0) {
    xj.x[i]=x; xj.bp[i]=bp; xj.z[i]=z; xj.el[i]=el; xj.er[i]=er; xj.N[i]=N; xj.t0[i]=t0;
  };
  setx(0, h_drug, pk[0], z_dd, el_r[0], er_r[0], ND, 0);   // dd
  setx(1, h_prot, pk[1], z_pd, el_r[1], nullptr, NP, 0);   // pd src
  setx(2, h_drug, pk[1], nullptr, nullptr, er_r[1], ND, 8);// pd dst
  setx(3, h_se,   pk[2], z_sd, el_r[2], nullptr, NS, 0);   // sd src
  setx(4, h_drug, pk[2], nullptr, nullptr, er_r[2], ND, 8);// sd dst
  setx(5, h_drug, pk[3], z_dp, el_r[3], nullptr, ND, 0);   // dp src
  setx(6, h_prot, pk[3], nullptr, nullptr, er_r[3], NP, 8);// dp dst
  setx(7, h_prot, pk[4], z_pp, el_r[4], er_r[4], NP, 0);   // pp
  int xblocks = 0;
  for (int i = 0; i < 8; ++i) { xj.blk0[i] = xblocks; xblocks += (xj.N[i] + 63) / 64; }
  xj.blk0[8] = xblocks;

  AJobs aj;
  const int ebase[5] = {0, 1000000, 2000000, 2500000, 3500000};
  const void* bias[5] = {b_dd, b_pd, b_sd, b_dp, b_pp};
  u16* fb[5] = {feats_d, feats_d + 128, feats_d + 256, feats_p, feats_p + 128};
  const int fstride[5] = {384, 384, 384, 256, 256};
  const int nsrc5[5] = {ND, NP, NS, ND, NP};
  const u16* zz[5] = {z_dd, z_pd, z_sd, z_dp, z_pp};
  for (int r = 0; r < 5; ++r) {
    aj.csr[r] = csr + ebase[r];
    aj.off[r] = offsets + r * CSTRIDE;
    aj.el[r] = el_r[r];
    aj.er[r] = er_r[r];
    aj.z[r] = zz[r];
    aj.b[r] = bias[r];
    aj.feats[r] = fb[r];
    aj.stride[r] = fstride[r];
    aj.nsrc[r] = nsrc5[r];
  }

  // ---- 7 launches, no memsets ----
  k_front<<<dim3(5 + NC), blk, 0, stream>>>(pj, ej, h_drug, ghist);
  k_mid<<<dim3(54 + NB), blk, 0, stream>>>(kp, h_drug, ghist, gcur, totals);
  k_bin<<<dim3(NC), blk, 0, stream>>>(ej, gcur, totals, bin);
  k_l4<<<dim3(NB + xblocks), blk, 0, stream>>>(xj, h_drug, bin, totals, csr, offsets);
  k_agg_all<<<dim3(75000), blk, 0, stream>>>(aj, h_drug);
  k_sem_all<<<dim3((150000 + 63) / 64), blk, 0, stream>>>(feats, pk[5], b1, W2, b2, s, 150000, h_drug);
  k_combine_all<<<dim3(15000), blk, 0, stream>>>(feats, s, d_out, h_drug);
}

// Round 11
// 534.210 us; speedup vs baseline: 1.1513x; 1.1513x over previous
//
#include <hip/hip_runtime.h>
#include <hip/hip_bf16.h>

typedef unsigned short u16;
typedef __attribute__((ext_vector_type(8))) short short8;   // 8 bf16 (4 VGPRs)
typedef __attribute__((ext_vector_type(4))) float f32x4;

#define ND 30000
#define NP 30000
#define NS 10000
#define CSTRIDE 30016          // offsets per-relation stride (ints)
#define ETOT 4500000
#define CHUNK 9216             // edges per chunk (36 per thread)
#define NC 489                 // ceil(ETOT/CHUNK)
#define NBR 118                // buckets per relation (256 dsts each)
#define NB 590                 // total buckets
#define NBD 1429               // drug semco blocks (21 nodes x 63 rows)
#define NBP 938                // prot semco blocks (32 nodes x 64 rows)

__device__ __forceinline__ float bf2f(u16 u) {
  union { unsigned int i; float f; } c; c.i = ((unsigned int)u) << 16; return c.f;
}
__device__ __forceinline__ u16 f2bf(float f) {
  union { float f; unsigned int i; } c; c.f = f;
  unsigned int u = c.i;
  unsigned int r = (u + 0x7fffu + ((u >> 16) & 1u)) >> 16;
  return (u16)r;
}

// Block-parallel input dtype detect (256 threads): for fp32 data the sampled
// u16s are mantissa halves (~16% sane exponent); bf16 ~100%.
__device__ __forceinline__ int detect_isbf(const void* x) {
  __shared__ int cnt4[4];
  const int tid = threadIdx.x;
  const u16 v = ((const u16*)x)[2 * tid];
  const int e = (v >> 7) & 0xff;
  const unsigned long long m = __ballot(e >= 100 && e <= 140);
  if ((tid & 63) == 0) cnt4[tid >> 6] = __popcll(m);
  __syncthreads();
  const int sane = cnt4[0] + cnt4[1] + cnt4[2] + cnt4[3];
  return sane >= 200;
}

__device__ __forceinline__ float ld_in(const void* p, int i, int isbf) {
  return isbf ? bf2f(((const u16*)p)[i]) : ((const float*)p)[i];
}

// ---------------------------------------------------------------------------
// Edge job tables
// ---------------------------------------------------------------------------
struct EJobs { const int* src[5]; const int* dst[5]; };
__device__ __forceinline__ int e_job(int e) {
  return (e >= 1000000) + (e >= 2000000) + (e >= 2500000) + (e >= 3500000);
}
__device__ __forceinline__ int e_base(int j) {
  const int base[6] = {0, 1000000, 2000000, 2500000, 3500000, 4500000};
  return base[j];
}

// ---------------------------------------------------------------------------
// prep: Wal[h][k] = sum_d W[k][h*16+d]*al[h*16+d] (and War with ar)
// ---------------------------------------------------------------------------
struct PJobs { const void* W[5]; const void* al[5]; const void* ar[5];
               float* wal[5]; float* war[5]; };
__device__ void prep_dev(const PJobs& J, int b, int isbf) {
  const int tid = threadIdx.x;
  if (tid >= 128) return;
  const int k = tid;
  for (int h = 0; h < 8; ++h) {
    float sa = 0.f, sr = 0.f;
    for (int d = 0; d < 16; ++d) {
      const float wv = ld_in(J.W[b], k * 128 + h * 16 + d, isbf);
      sa = fmaf(wv, ld_in(J.al[b], h * 16 + d, isbf), sa);
      sr = fmaf(wv, ld_in(J.ar[b], h * 16 + d, isbf), sr);
    }
    J.wal[b][h * 128 + k] = sa;
    J.war[b][h * 128 + k] = sr;
  }
}

// ---------------------------------------------------------------------------
// hist: per-chunk bucket histogram (LDS atomics only)
// ---------------------------------------------------------------------------
__device__ void hist_dev(const EJobs& J, int* __restrict__ ghist, int c) {
  __shared__ int hsh[NB];
  const int tid = threadIdx.x;
  for (int i = tid; i < NB; i += 256) hsh[i] = 0;
  __syncthreads();
  const int e0 = c * CHUNK;
  #pragma unroll 4
  for (int t = 0; t < 36; ++t) {
    const int e = e0 + t * 256 + tid;
    if (e < ETOT) {
      const int j = e_job(e);
      const int d = J.dst[j][e - e_base(j)];
      atomicAdd(&hsh[j * NBR + (d >> 8)], 1);
    }
  }
  __syncthreads();
  for (int i = tid; i < NB; i += 256) ghist[c * NB + i] = hsh[i];
}

// k_front: blocks 0..4 = prep, 5.. = hist
__global__ __launch_bounds__(256) void k_front(PJobs PJ, EJobs EJ,
    const void* xdet, int* __restrict__ ghist) {
  if (blockIdx.x < 5) {
    const int isbf = detect_isbf(xdet);
    prep_dev(PJ, blockIdx.x, isbf);
  } else {
    hist_dev(EJ, ghist, blockIdx.x - 5);
  }
}

// ---------------------------------------------------------------------------
// pack: B matrices into MFMA fragment order (jobs 0..4 = W|Wal|War, 5 = W1)
// ---------------------------------------------------------------------------
struct KPack { const void* W[6]; const float* wal[6]; const float* war[6];
               u16* out[6]; };
__device__ void pack_dev(const KPack& J, int b, int isbf) {
  const int job = b / 9;
  const int i0 = (b % 9) * 2048 + threadIdx.x * 8;
  const int kc = i0 / 4608;
  const int rem = i0 - kc * 4608;
  const int n = rem >> 5;
  const int q = (rem >> 3) & 3;
  u16 vals[8];
  #pragma unroll
  for (int j = 0; j < 8; ++j) {
    const int k = kc * 32 + q * 8 + j;
    float v;
    if (job == 5)      v = (n < 128) ? ld_in(J.W[5], k * 128 + n, isbf) : 0.f;
    else if (n < 128)  v = ld_in(J.W[job], k * 128 + n, isbf);
    else if (n < 136)  v = J.wal[job][(n - 128) * 128 + k];
    else               v = J.war[job][(n - 136) * 128 + k];
    vals[j] = f2bf(v);
  }
  *(uint4*)&J.out[job][i0] = *(uint4*)vals;
}

// bucketscan: per bucket, prefix over chunks
__device__ void bucketscan_dev(const int* __restrict__ ghist,
    int* __restrict__ gcur, int* __restrict__ totals, int b) {
  __shared__ int ts[256];
  const int tid = threadIdx.x;
  int v0 = 0, v1 = 0;
  const int c0 = tid * 2;
  if (c0 < NC) v0 = ghist[c0 * NB + b];
  if (c0 + 1 < NC) v1 = ghist[(c0 + 1) * NB + b];
  ts[tid] = v0 + v1;
  __syncthreads();
  for (int o = 1; o < 256; o <<= 1) {
    const int x = (tid >= o) ? ts[tid - o] : 0;
    __syncthreads();
    ts[tid] += x;
    __syncthreads();
  }
  int run = (tid == 0) ? 0 : ts[tid - 1];
  if (c0 < NC) { gcur[b * NC + c0] = run; run += v0; }
  if (c0 + 1 < NC) gcur[b * NC + c0 + 1] = run;
  if (tid == 255) totals[b] = ts[255];
}

// k_mid: blocks 0..53 = pack, 54.. = bucketscan
__global__ __launch_bounds__(256) void k_mid(KPack KJ, const void* xdet,
    const int* __restrict__ ghist, int* __restrict__ gcur, int* __restrict__ totals) {
  if (blockIdx.x < 54) {
    const int isbf = detect_isbf(xdet);
    pack_dev(KJ, blockIdx.x, isbf);
  } else {
    bucketscan_dev(ghist, gcur, totals, blockIdx.x - 54);
  }
}

// ---------------------------------------------------------------------------
// base prefix over the 590 bucket totals, recomputed in LDS (tiny)
// ---------------------------------------------------------------------------
__device__ void base_from_totals(const int* __restrict__ totals, int* bsh) {
  __shared__ int ts[256];
  const int tid = threadIdx.x;
  const int i0 = tid * 3;
  int v0 = 0, v1 = 0, v2 = 0;
  if (i0 < NB) v0 = totals[i0];
  if (i0 + 1 < NB) v1 = totals[i0 + 1];
  if (i0 + 2 < NB) v2 = totals[i0 + 2];
  ts[tid] = v0 + v1 + v2;
  __syncthreads();
  for (int o = 1; o < 256; o <<= 1) {
    const int x = (tid >= o) ? ts[tid - o] : 0;
    __syncthreads();
    ts[tid] += x;
    __syncthreads();
  }
  int run = (tid == 0) ? 0 : ts[tid - 1];
  if (i0 < NB) { bsh[i0] = run; run += v0; }
  if (i0 + 1 < NB) { bsh[i0 + 1] = run; run += v1; }
  if (i0 + 2 < NB) bsh[i0 + 2] = run;
  if (tid == 0) bsh[NB] = ETOT;
  __syncthreads();
}

// ---------------------------------------------------------------------------
// bin: scatter (dst&255 | src) into bucket-ordered runs (LDS cursors)
// ---------------------------------------------------------------------------
__global__ __launch_bounds__(256) void k_bin(EJobs J,
    const int* __restrict__ gcur, const int* __restrict__ totals,
    unsigned int* __restrict__ bin) {
  __shared__ int bsh[NB + 1];
  __shared__ int cur[NB];
  base_from_totals(totals, bsh);
  const int c = blockIdx.x, tid = threadIdx.x;
  for (int i = tid; i < NB; i += 256) cur[i] = bsh[i] + gcur[i * NC + c];
  __syncthreads();
  const int e0 = c * CHUNK;
  #pragma unroll 4
  for (int t = 0; t < 36; ++t) {
    const int e = e0 + t * 256 + tid;
    if (e < ETOT) {
      const int j = e_job(e);
      const int le = e - e_base(j);
      const int d = J.dst[j][le];
      const int s = J.src[j][le];
      const int pos = atomicAdd(&cur[j * NBR + (d >> 8)], 1);
      bin[pos] = ((unsigned int)(d & 255) << 16) | (unsigned int)s;
    }
  }
}

// ---------------------------------------------------------------------------
// fill2: per bucket, sort 256 dsts in LDS, emit u16 CSR + offsets
// ---------------------------------------------------------------------------
__device__ void fill2_dev(const unsigned int* __restrict__ bin,
    const int* __restrict__ totals, u16* __restrict__ csr,
    int* __restrict__ offsets, int b) {
  __shared__ int bsh2[NB + 1];
  __shared__ int cnt[256], curs[256];
  base_from_totals(totals, bsh2);
  const int tid = threadIdx.x;
  const int rel = b / NBR;
  const int bloc = b - rel * NBR;
  const int d0 = bloc << 8;
  const int gbeg = bsh2[b];
  const int n = bsh2[b + 1] - gbeg;
  cnt[tid] = 0;
  __syncthreads();
  for (int i = tid; i < n; i += 256)
    atomicAdd(&cnt[bin[gbeg + i] >> 16], 1);
  __syncthreads();
  const int orig = cnt[tid];
  for (int o = 1; o < 256; o <<= 1) {
    const int x = (tid >= o) ? cnt[tid - o] : 0;
    __syncthreads();
    cnt[tid] += x;
    __syncthreads();
  }
  const int ex = cnt[tid] - orig;
  curs[tid] = ex;
  const int ebr = e_base(rel);
  const int d = d0 + tid;
  if (d < 30000) offsets[rel * CSTRIDE + d] = (gbeg - ebr) + ex;
  if (bloc == NBR - 1 && tid == 0)
    offsets[rel * CSTRIDE + 30000] = e_base(rel + 1) - ebr;
  __syncthreads();
  for (int i = tid; i < n; i += 256) {
    const unsigned int v = bin[gbeg + i];
    const int pos = atomicAdd(&curs[v >> 16], 1);
    csr[gbeg + pos] = (u16)(v & 0xffffu);
  }
}

// ---------------------------------------------------------------------------
// MFMA transform (R6/R9-proven): [Nx128]@[128x144]; tiles 0..7->z (unified
// row layout), 8->el/er.
// ---------------------------------------------------------------------------
struct XJobs {
  const void* x[8]; const u16* bp[8]; u16* z[8]; float* el[8]; float* er[8];
  int N[8]; int t0[8]; int blk0[9];
};
__device__ void xform_dev(const XJobs& J, int xb, int isbf) {
  __shared__ __align__(16) u16 Bf[18432];
  __shared__ __align__(16) u16 As[64 * 136];
  const int tid = threadIdx.x;
  int job = 0;
  while (xb >= J.blk0[job + 1]) ++job;
  const int row0 = (xb - J.blk0[job]) * 64;
  const int N = J.N[job];
  const int t0 = J.t0[job];
  const u16* bp = J.bp[job];
  const void* x = J.x[job];

  if (t0 == 0) {
    for (int i = tid * 8; i < 18432; i += 2048)
      *(uint4*)&Bf[i] = *(const uint4*)&bp[i];
  } else {
    const int i = tid * 8;
    const int kc = i >> 9;
    const int off = (kc * 144 + 128) * 32 + (i & 511);
    *(uint4*)&Bf[off] = *(const uint4*)&bp[off];
  }

  if (isbf) {
    const uint4* xv = (const uint4*)x;
    for (int i = tid; i < 1024; i += 256) {
      const int r = i >> 4, c8 = i & 15;
      const int row = row0 + r;
      uint4 v = make_uint4(0, 0, 0, 0);
      if (row < N) v = xv[row * 16 + c8];
      *(uint4*)&As[r * 136 + c8 * 8] = v;
    }
  } else {
    const float4* xf = (const float4*)x;
    for (int i = tid; i < 2048; i += 256) {
      const int r = i >> 5, c4 = i & 31;
      const int row = row0 + r;
      unsigned long long pkv = 0ull;
      if (row < N) {
        const float4 v = xf[row * 32 + c4];
        pkv = (unsigned long long)f2bf(v.x) | ((unsigned long long)f2bf(v.y) << 16)
            | ((unsigned long long)f2bf(v.z) << 32) | ((unsigned long long)f2bf(v.w) << 48);
      }
      *(unsigned long long*)&As[r * 136 + c4 * 4] = pkv;
    }
  }
  __syncthreads();

  const int wave = tid >> 6;
  const int lane = tid & 63;
  const int q = lane >> 4;
  const int c = lane & 15;

  f32x4 accT[8];
  f32x4 acc8 = (f32x4){0.f, 0.f, 0.f, 0.f};
  if (t0 == 0) {
    #pragma unroll
    for (int t = 0; t < 8; ++t) accT[t] = (f32x4){0.f, 0.f, 0.f, 0.f};
  }

  #pragma unroll
  for (int kc = 0; kc < 4; ++kc) {
    const short8 a = *(const short8*)&As[(wave * 16 + c) * 136 + kc * 32 + q * 8];
    if (t0 == 0) {
      #pragma unroll
      for (int t = 0; t < 8; ++t) {
        const short8 bb = *(const short8*)&Bf[((kc * 144 + t * 16 + c) * 4 + q) * 8];
        accT[t] = __builtin_amdgcn_mfma_f32_16x16x32_bf16(a, bb, accT[t], 0, 0, 0);
      }
    }
    const short8 b8 = *(const short8*)&Bf[((kc * 144 + 128 + c) * 4 + q) * 8];
    acc8 = __builtin_amdgcn_mfma_f32_16x16x32_bf16(a, b8, acc8, 0, 0, 0);
  }

  const int rbase = row0 + wave * 16 + q * 4;
  if (t0 == 0 && J.z[job]) {
    u16* zo = J.z[job];
    #pragma unroll
    for (int t = 0; t < 8; ++t)
      #pragma unroll
      for (int r = 0; r < 4; ++r) {
        const int row = rbase + r;
        if (row < N) zo[row * 128 + t * 16 + c] = f2bf(accT[t][r]);
      }
  }
  #pragma unroll
  for (int r = 0; r < 4; ++r) {
    const int row = rbase + r;
    if (row < N) {
      const float v = acc8[r];
      if (c < 8) { if (J.el[job]) J.el[job][row * 8 + c] = v; }
      else       { if (J.er[job]) J.er[job][row * 8 + (c - 8)] = v; }
    }
  }
}

// k_l4: blocks 0..589 = fill2, 590.. = xform
__global__ __launch_bounds__(256) void k_l4(XJobs XJ, const void* xdet,
    const unsigned int* __restrict__ bin, const int* __restrict__ totals,
    u16* __restrict__ csr, int* __restrict__ offsets) {
  if (blockIdx.x < NB) {
    fill2_dev(bin, totals, csr, offsets, blockIdx.x);
  } else {
    const int isbf = detect_isbf(xdet);
    xform_dev(XJ, blockIdx.x - NB, isbf);
  }
}

// ---------------------------------------------------------------------------
// Aggregation (R9-proven): one wave per (relation, dst). 8 edges/window;
// lane (h,i) computes ex once; phases maximize outstanding loads:
// csr -> 8 readlane -> 8 z loads back-to-back -> 8 bpermute -> 16 FMA.
// ---------------------------------------------------------------------------
struct AJobs { const u16* csr[5]; const int* off[5]; const float* el[5];
               const float* er[5]; const u16* z[5]; const void* b[5];
               u16* feats[5]; int stride[5]; };
__global__ __launch_bounds__(256) void k_agg_all(AJobs J, const void* xdet) {
  const int isbf = detect_isbf(xdet);
  const int gw = (blockIdx.x * 256 + threadIdx.x) >> 6;
  const int lane = threadIdx.x & 63;
  const int job = gw / 30000;
  const int d = gw - job * 30000;
  const int h = lane >> 3;            // head of this lane's feature pair
  const int i8 = lane & 7;            // which of 8 edges this lane exps
  const float* el = J.el[job];
  const u16* ztl = J.z[job] + lane * 2;   // per-lane z base
  const u16* csr = J.csr[job];
  const float erh = J.er[job][d * 8 + h];
  const int beg = J.off[job][d];
  const int end = J.off[job][d + 1];
  const int gb4 = (lane & 56) << 2;   // bpermute byte base of this h-group

  float a0 = 0.f, a1 = 0.f, denP = 0.f;
  for (int p = beg; p < end; p += 8) {
    const int idx = p + i8;
    const bool valid = (idx < end);
    const int sE = (int)csr[valid ? idx : (end - 1)];
    float eh = el[sE * 8 + h] + erh;
    eh = fminf(fmaxf(eh, 0.2f * eh), 60.f);   // leaky_relu + clamp
    const float exE = valid ? __expf(eh) : 0.f;
    denP += exE;
    int si[8];
    #pragma unroll
    for (int i = 0; i < 8; ++i) si[i] = __builtin_amdgcn_readlane(sE, i);
    unsigned int zp[8];
    #pragma unroll
    for (int i = 0; i < 8; ++i)
      zp[i] = *(const unsigned int*)(ztl + si[i] * 128);
    const int exb = __float_as_int(exE);
    float exi[8];
    #pragma unroll
    for (int i = 0; i < 8; ++i)
      exi[i] = __int_as_float(__builtin_amdgcn_ds_bpermute(gb4 + i * 4, exb));
    #pragma unroll
    for (int i = 0; i < 8; ++i) {
      union { unsigned int u; float f; } lo, hi;
      lo.u = zp[i] << 16; hi.u = zp[i] & 0xffff0000u;
      a0 = fmaf(exi[i], lo.f, a0);
      a1 = fmaf(exi[i], hi.f, a1);
    }
  }
  denP += __shfl_xor(denP, 1);
  denP += __shfl_xor(denP, 2);
  denP += __shfl_xor(denP, 4);        // full den(h) within the 8-lane group
  const float inv = 1.f / fmaxf(denP, 1e-9f);
  const int j0 = lane * 2;
  const float v0 = a0 * inv + ld_in(J.b[job], j0, isbf);
  const float v1 = a1 * inv + ld_in(J.b[job], j0 + 1, isbf);
  const unsigned int packed = (unsigned int)f2bf(v0) | ((unsigned int)f2bf(v1) << 16);
  *(unsigned int*)(J.feats[job] + d * J.stride[job] + j0) = packed;
}

// ---------------------------------------------------------------------------
// Fused semantic score + combine. Node-aligned M-tiles: drug blocks = 63 rows
// (21 nodes x R=3), prot blocks = 64 rows (32 nodes x R=2). Scores -> LDS,
// per-node softmax (b2 drops out by shift invariance), then combine directly
// from the As LDS tile (feats already staged) -> output. No s buffer, no
// second feats read, no separate combine launch.
// ---------------------------------------------------------------------------
__global__ __launch_bounds__(256) void k_semco(
    const u16* __restrict__ f, const u16* __restrict__ w1pack,
    const void* __restrict__ b1, const void* __restrict__ W2,
    void* __restrict__ out, const void* xdet)
{
  __shared__ __align__(16) u16 Bf[18432];
  __shared__ __align__(16) u16 As[64 * 136];
  __shared__ float b1S[128], W2S[128];
  __shared__ float sS[64];
  __shared__ float wS[128];
  const int isbf = detect_isbf(xdet);
  const int tid = threadIdx.x;
  const bool drug = (blockIdx.x < NBD);
  const int bloc = drug ? blockIdx.x : blockIdx.x - NBD;
  const int row0 = drug ? bloc * 63 : 90000 + bloc * 64;
  const int rowLim = drug ? 90000 : 150000;

  for (int i = tid * 8; i < 18432; i += 2048)
    *(uint4*)&Bf[i] = *(const uint4*)&w1pack[i];
  if (tid < 128) { b1S[tid] = ld_in(b1, tid, isbf); W2S[tid] = ld_in(W2, tid, isbf); }
  {
    const uint4* xv = (const uint4*)f;
    for (int i = tid; i < 1024; i += 256) {
      const int r = i >> 4, c8 = i & 15;
      const int row = row0 + r;
      uint4 v = make_uint4(0, 0, 0, 0);
      if (row < rowLim) v = xv[row * 16 + c8];
      *(uint4*)&As[r * 136 + c8 * 8] = v;
    }
  }
  __syncthreads();

  const int wave = tid >> 6;
  const int lane = tid & 63;
  const int q = lane >> 4;
  const int c = lane & 15;

  f32x4 acc[8];
  #pragma unroll
  for (int t = 0; t < 8; ++t) acc[t] = (f32x4){0.f, 0.f, 0.f, 0.f};

  #pragma unroll
  for (int kc = 0; kc < 4; ++kc) {
    const short8 a = *(const short8*)&As[(wave * 16 + c) * 136 + kc * 32 + q * 8];
    #pragma unroll
    for (int t = 0; t < 8; ++t) {
      const short8 bb = *(const short8*)&Bf[((kc * 144 + t * 16 + c) * 4 + q) * 8];
      acc[t] = __builtin_amdgcn_mfma_f32_16x16x32_bf16(a, bb, acc[t], 0, 0, 0);
    }
  }

  float part[4] = {0.f, 0.f, 0.f, 0.f};
  #pragma unroll
  for (int t = 0; t < 8; ++t) {
    const int n = t * 16 + c;
    const float b1v = b1S[n];
    const float w2v = W2S[n];
    #pragma unroll
    for (int r = 0; r < 4; ++r) {
      const float hv = acc[t][r] + b1v;
      const float e = __expf(2.f * hv);
      const float th = 1.f - 2.f / (e + 1.f);   // tanh, overflow-safe
      part[r] = fmaf(th, w2v, part[r]);
    }
  }
  #pragma unroll
  for (int r = 0; r < 4; ++r) {
    part[r] += __shfl_xor(part[r], 1);
    part[r] += __shfl_xor(part[r], 2);
    part[r] += __shfl_xor(part[r], 4);
    part[r] += __shfl_xor(part[r], 8);
  }
  if (c == 0) {
    #pragma unroll
    for (int r = 0; r < 4; ++r)
      sS[wave * 16 + q * 4 + r] = part[r];      // b2 omitted: softmax-invariant
  }
  __syncthreads();

  // ---- per-node softmax over relation scores ----
  const int R = drug ? 3 : 2;
  const int nmax = drug ? 21 : 32;
  int nnode = 30000 - bloc * nmax;
  if (nnode > nmax) nnode = nmax;
  if (tid < nnode) {
    const float s0v = sS[tid * R];
    const float s1v = sS[tid * R + 1];
    const float s2v = (R == 3) ? sS[tid * R + 2] : -3.4e38f;
    const float mx = fmaxf(fmaxf(s0v, s1v), s2v);
    const float w0 = __expf(s0v - mx);
    const float w1 = __expf(s1v - mx);
    const float w2 = (R == 3) ? __expf(s2v - mx) : 0.f;
    const float inv = 1.f / (w0 + w1 + w2);
    wS[tid * 4 + 0] = w0 * inv;
    wS[tid * 4 + 1] = w1 * inv;
    wS[tid * 4 + 2] = w2 * inv;
  }
  __syncthreads();

  // ---- combine from the As tile (feats already in LDS) ----
  const int node0 = bloc * nmax;
  const int tot = nnode * 64;                   // u32-pair outputs
  for (int idx = tid; idx < tot; idx += 256) {
    const int node = idx >> 6;
    const int j2 = idx & 63;
    const int lr = node * R;
    const float w0 = wS[node * 4], w1 = wS[node * 4 + 1], w2 = wS[node * 4 + 2];
    const unsigned int f0 = *(const unsigned int*)&As[lr * 136 + j2 * 2];
    const unsigned int f1 = *(const unsigned int*)&As[(lr + 1) * 136 + j2 * 2];
    union { unsigned int u; float ff; } t;
    float acc0, acc1;
    t.u = f0 << 16;          acc0 = w0 * t.ff;
    t.u = f0 & 0xffff0000u;  acc1 = w0 * t.ff;
    t.u = f1 << 16;          acc0 = fmaf(w1, t.ff, acc0);
    t.u = f1 & 0xffff0000u;  acc1 = fmaf(w1, t.ff, acc1);
    if (drug) {
      const unsigned int f2v = *(const unsigned int*)&As[(lr + 2) * 136 + j2 * 2];
      t.u = f2v << 16;         acc0 = fmaf(w2, t.ff, acc0);
      t.u = f2v & 0xffff0000u; acc1 = fmaf(w2, t.ff, acc1);
    }
    const int oi = (drug ? 0 : 1920000) + (node0 + node) * 64 + j2;
    if (isbf) {
      ((unsigned int*)out)[oi] =
          (unsigned int)f2bf(acc0) | ((unsigned int)f2bf(acc1) << 16);
    } else {
      float2 v; v.x = acc0; v.y = acc1;
      ((float2*)out)[oi] = v;
    }
  }
}

extern "C" void kernel_launch(void* const* d_in, const int* in_sizes, int n_in,
                              void* d_out, int out_size, void* d_ws, size_t ws_size,
                              hipStream_t stream)
{
  (void)in_sizes; (void)n_in; (void)out_size; (void)ws_size;

  const void* h_drug = d_in[0];
  const void* h_prot = d_in[1];
  const void* h_se   = d_in[2];
  const void* W_dd = d_in[3];  const void* al_dd = d_in[4];
  const void* ar_dd = d_in[5]; const void* b_dd  = d_in[6];
  const void* W_dp = d_in[7];  const void* al_dp = d_in[8];
  const void* ar_dp = d_in[9]; const void* b_dp  = d_in[10];
  const void* W_pd = d_in[11]; const void* al_pd = d_in[12];
  const void* ar_pd = d_in[13];const void* b_pd  = d_in[14];
  const void* W_pp = d_in[15]; const void* al_pp = d_in[16];
  const void* ar_pp = d_in[17];const void* b_pp  = d_in[18];
  const void* W_sd = d_in[19]; const void* al_sd = d_in[20];
  const void* ar_sd = d_in[21];const void* b_sd  = d_in[22];
  const void* W1 = d_in[23];   const void* b1 = d_in[24];
  const void* W2 = d_in[25];   const void* b2 = d_in[26];
  (void)b2;  // cancels in relation softmax (shift invariance)
  const int* src_dd = (const int*)d_in[27];
  const int* dst_dd = (const int*)d_in[28];
  const int* src_dp = (const int*)d_in[29];
  const int* dst_dp = (const int*)d_in[30];
  const int* src_pd = (const int*)d_in[31];
  const int* dst_pd = (const int*)d_in[32];
  const int* src_pp = (const int*)d_in[33];
  const int* dst_pp = (const int*)d_in[34];
  const int* src_sd = (const int*)d_in[35];
  const int* dst_sd = (const int*)d_in[36];

  // ---- workspace layout (~94.1 MB <= 101.4 MB proven in R6) ----
  char* w = (char*)d_ws;
  float* el5   = (float*)(w);                    // 4,800,000
  float* er5   = (float*)(w + 4800000);          // 4,800,000
  u16* z_dd    = (u16*)(w + 9600000);            // 7,680,000
  u16* z_pd    = (u16*)(w + 17280000);           // 7,680,000
  u16* z_sd    = (u16*)(w + 24960000);           // 2,560,000
  u16* z_dp    = (u16*)(w + 27520000);           // 7,680,000
  u16* z_pp    = (u16*)(w + 35200000);           // 7,680,000
  int* offsets = (int*)(w + 42880000);           // 600,320
  u16* csr     = (u16*)(w + 43480320);           // 9,000,000
  int* ghist   = (int*)(w + 52480320);           // 1,154,040
  int* gcur    = (int*)(w + 53634560);           // 1,154,040
  int* totals  = (int*)(w + 54788608);           // 2,360
  u16* feats   = (u16*)(w + 55391232);           // 38,400,000 (16B aligned)
  unsigned int* bin = (unsigned int*)(w + 55391232); // aliases feats (dead before agg)
  float* ww    = (float*)(w + 93791232);         // 40,960 (wal/war x5)
  u16* packs   = (u16*)(w + 93832192);           // 221,184 -> end 94,053,376

  float *wal[5], *war[5];
  for (int r = 0; r < 5; ++r) { wal[r] = ww + r * 2048; war[r] = ww + r * 2048 + 1024; }
  u16* pk[6];
  for (int r = 0; r < 6; ++r) pk[r] = packs + r * 18432;
  float* el_r[5]; float* er_r[5];
  for (int r = 0; r < 5; ++r) { el_r[r] = el5 + r * 240000; er_r[r] = er5 + r * 240000; }
  u16* feats_d = feats;               // drug: 30000 x 384
  u16* feats_p = feats + 11520000;    // prot: 30000 x 256

  const dim3 blk(256);

  // rel order: 0=dd 1=pd 2=sd 3=dp 4=pp
  PJobs pj;
  pj.W[0]=W_dd; pj.al[0]=al_dd; pj.ar[0]=ar_dd;
  pj.W[1]=W_pd; pj.al[1]=al_pd; pj.ar[1]=ar_pd;
  pj.W[2]=W_sd; pj.al[2]=al_sd; pj.ar[2]=ar_sd;
  pj.W[3]=W_dp; pj.al[3]=al_dp; pj.ar[3]=ar_dp;
  pj.W[4]=W_pp; pj.al[4]=al_pp; pj.ar[4]=ar_pp;
  for (int r = 0; r < 5; ++r) { pj.wal[r] = wal[r]; pj.war[r] = war[r]; }

  EJobs ej;
  ej.src[0]=src_dd; ej.dst[0]=dst_dd;
  ej.src[1]=src_pd; ej.dst[1]=dst_pd;
  ej.src[2]=src_sd; ej.dst[2]=dst_sd;
  ej.src[3]=src_dp; ej.dst[3]=dst_dp;
  ej.src[4]=src_pp; ej.dst[4]=dst_pp;

  KPack kp;
  kp.W[0]=W_dd; kp.W[1]=W_pd; kp.W[2]=W_sd; kp.W[3]=W_dp; kp.W[4]=W_pp; kp.W[5]=W1;
  for (int r = 0; r < 5; ++r) { kp.wal[r] = wal[r]; kp.war[r] = war[r]; }
  kp.wal[5]=nullptr; kp.war[5]=nullptr;
  for (int r = 0; r < 6; ++r) kp.out[r] = pk[r];

  XJobs xj;
  auto setx = [&](int i, const void* x, const u16* bp, u16* z, float* el,
                  float* er, int N, int t0) {
    xj.x[i]=x; xj.bp[i]=bp; xj.z[i]=z; xj.el[i]=el; xj.er[i]=er; xj.N[i]=N; xj.t0[i]=t0;
  };
  setx(0, h_drug, pk[0], z_dd, el_r[0], er_r[0], ND, 0);   // dd
  setx(1, h_prot, pk[1], z_pd, el_r[1], nullptr, NP, 0);   // pd src
  setx(2, h_drug, pk[1], nullptr, nullptr, er_r[1], ND, 8);// pd dst
  setx(3, h_se,   pk[2], z_sd, el_r[2], nullptr, NS, 0);   // sd src
  setx(4, h_drug, pk[2], nullptr, nullptr, er_r[2], ND, 8);// sd dst
  setx(5, h_drug, pk[3], z_dp, el_r[3], nullptr, ND, 0);   // dp src
  setx(6, h_prot, pk[3], nullptr, nullptr, er_r[3], NP, 8);// dp dst
  setx(7, h_prot, pk[4], z_pp, el_r[4], er_r[4], NP, 0);   // pp
  int xblocks = 0;
  for (int i = 0; i < 8; ++i) { xj.blk0[i] = xblocks; xblocks += (xj.N[i] + 63) / 64; }
  xj.blk0[8] = xblocks;

  AJobs aj;
  const int ebase[5] = {0, 1000000, 2000000, 2500000, 3500000};
  const void* bias[5] = {b_dd, b_pd, b_sd, b_dp, b_pp};
  u16* fb[5] = {feats_d, feats_d + 128, feats_d + 256, feats_p, feats_p + 128};
  const int fstride[5] = {384, 384, 384, 256, 256};
  const u16* zz[5] = {z_dd, z_pd, z_sd, z_dp, z_pp};
  for (int r = 0; r < 5; ++r) {
    aj.csr[r] = csr + ebase[r];
    aj.off[r] = offsets + r * CSTRIDE;
    aj.el[r] = el_r[r];
    aj.er[r] = er_r[r];
    aj.z[r] = zz[r];
    aj.b[r] = bias[r];
    aj.feats[r] = fb[r];
    aj.stride[r] = fstride[r];
  }

  // ---- 6 launches, no memsets ----
  k_front<<<dim3(5 + NC), blk, 0, stream>>>(pj, ej, h_drug, ghist);
  k_mid<<<dim3(54 + NB), blk, 0, stream>>>(kp, h_drug, ghist, gcur, totals);
  k_bin<<<dim3(NC), blk, 0, stream>>>(ej, gcur, totals, bin);
  k_l4<<<dim3(NB + xblocks), blk, 0, stream>>>(xj, h_drug, bin, totals, csr, offsets);
  k_agg_all<<<dim3(37500), blk, 0, stream>>>(aj, h_drug);
  k_semco<<<dim3(NBD + NBP), blk, 0, stream>>>(feats, pk[5], b1, W2, d_out, h_drug);
}

// Round 12
// 523.548 us; speedup vs baseline: 1.1748x; 1.0204x over previous
//
#include <hip/hip_runtime.h>
#include <hip/hip_bf16.h>

typedef unsigned short u16;
typedef __attribute__((ext_vector_type(8))) short short8;   // 8 bf16 (4 VGPRs)
typedef __attribute__((ext_vector_type(4))) float f32x4;

#define ND 30000
#define NP 30000
#define NS 10000
#define CSTRIDE 30016          // offsets per-relation stride (ints)
#define ETOT 4500000
#define CHUNK 9216             // edges per chunk (36 per thread)
#define NC 489                 // ceil(ETOT/CHUNK)
#define NBR 118                // buckets per relation (256 dsts each)
#define NB 590                 // total buckets
#define NBD 1429               // drug semco blocks (21 nodes x 63 rows)
#define NBP 938                // prot semco blocks (32 nodes x 64 rows)

__device__ __forceinline__ float bf2f(u16 u) {
  union { unsigned int i; float f; } c; c.i = ((unsigned int)u) << 16; return c.f;
}
__device__ __forceinline__ u16 f2bf(float f) {
  union { float f; unsigned int i; } c; c.f = f;
  unsigned int u = c.i;
  unsigned int r = (u + 0x7fffu + ((u >> 16) & 1u)) >> 16;
  return (u16)r;
}

// Block-parallel input dtype detect (256 threads): for fp32 data the sampled
// u16s are mantissa halves (~16% sane exponent); bf16 ~100%.
__device__ __forceinline__ int detect_isbf(const void* x) {
  __shared__ int cnt4[4];
  const int tid = threadIdx.x;
  const u16 v = ((const u16*)x)[2 * tid];
  const int e = (v >> 7) & 0xff;
  const unsigned long long m = __ballot(e >= 100 && e <= 140);
  if ((tid & 63) == 0) cnt4[tid >> 6] = __popcll(m);
  __syncthreads();
  const int sane = cnt4[0] + cnt4[1] + cnt4[2] + cnt4[3];
  return sane >= 200;
}

__device__ __forceinline__ float ld_in(const void* p, int i, int isbf) {
  return isbf ? bf2f(((const u16*)p)[i]) : ((const float*)p)[i];
}

// ---------------------------------------------------------------------------
// Edge job tables
// ---------------------------------------------------------------------------
struct EJobs { const int* src[5]; const int* dst[5]; };
__device__ __forceinline__ int e_job(int e) {
  return (e >= 1000000) + (e >= 2000000) + (e >= 2500000) + (e >= 3500000);
}
__device__ __forceinline__ int e_base(int j) {
  const int base[6] = {0, 1000000, 2000000, 2500000, 3500000, 4500000};
  return base[j];
}

// ---------------------------------------------------------------------------
// prep: Wal[h][k] = sum_d W[k][h*16+d]*al[h*16+d] (and War with ar)
// ---------------------------------------------------------------------------
struct PJobs { const void* W[5]; const void* al[5]; const void* ar[5];
               float* wal[5]; float* war[5]; };
__device__ void prep_dev(const PJobs& J, int b, int isbf) {
  const int tid = threadIdx.x;
  if (tid >= 128) return;
  const int k = tid;
  for (int h = 0; h < 8; ++h) {
    float sa = 0.f, sr = 0.f;
    for (int d = 0; d < 16; ++d) {
      const float wv = ld_in(J.W[b], k * 128 + h * 16 + d, isbf);
      sa = fmaf(wv, ld_in(J.al[b], h * 16 + d, isbf), sa);
      sr = fmaf(wv, ld_in(J.ar[b], h * 16 + d, isbf), sr);
    }
    J.wal[b][h * 128 + k] = sa;
    J.war[b][h * 128 + k] = sr;
  }
}

// ---------------------------------------------------------------------------
// hist: per-chunk bucket histogram (LDS atomics only)
// ---------------------------------------------------------------------------
__device__ void hist_dev(const EJobs& J, int* __restrict__ ghist, int c) {
  __shared__ int hsh[NB];
  const int tid = threadIdx.x;
  for (int i = tid; i < NB; i += 256) hsh[i] = 0;
  __syncthreads();
  const int e0 = c * CHUNK;
  #pragma unroll 4
  for (int t = 0; t < 36; ++t) {
    const int e = e0 + t * 256 + tid;
    if (e < ETOT) {
      const int j = e_job(e);
      const int d = J.dst[j][e - e_base(j)];
      atomicAdd(&hsh[j * NBR + (d >> 8)], 1);
    }
  }
  __syncthreads();
  for (int i = tid; i < NB; i += 256) ghist[c * NB + i] = hsh[i];
}

// k_front: blocks 0..4 = prep, 5.. = hist
__global__ __launch_bounds__(256) void k_front(PJobs PJ, EJobs EJ,
    const void* xdet, int* __restrict__ ghist) {
  if (blockIdx.x < 5) {
    const int isbf = detect_isbf(xdet);
    prep_dev(PJ, blockIdx.x, isbf);
  } else {
    hist_dev(EJ, ghist, blockIdx.x - 5);
  }
}

// ---------------------------------------------------------------------------
// pack: B matrices into MFMA fragment order (jobs 0..4 = W|Wal|War, 5 = W1)
// ---------------------------------------------------------------------------
struct KPack { const void* W[6]; const float* wal[6]; const float* war[6];
               u16* out[6]; };
__device__ void pack_dev(const KPack& J, int b, int isbf) {
  const int job = b / 9;
  const int i0 = (b % 9) * 2048 + threadIdx.x * 8;
  const int kc = i0 / 4608;
  const int rem = i0 - kc * 4608;
  const int n = rem >> 5;
  const int q = (rem >> 3) & 3;
  u16 vals[8];
  #pragma unroll
  for (int j = 0; j < 8; ++j) {
    const int k = kc * 32 + q * 8 + j;
    float v;
    if (job == 5)      v = (n < 128) ? ld_in(J.W[5], k * 128 + n, isbf) : 0.f;
    else if (n < 128)  v = ld_in(J.W[job], k * 128 + n, isbf);
    else if (n < 136)  v = J.wal[job][(n - 128) * 128 + k];
    else               v = J.war[job][(n - 136) * 128 + k];
    vals[j] = f2bf(v);
  }
  *(uint4*)&J.out[job][i0] = *(uint4*)vals;
}

// bucketscan: per bucket, prefix over chunks
__device__ void bucketscan_dev(const int* __restrict__ ghist,
    int* __restrict__ gcur, int* __restrict__ totals, int b) {
  __shared__ int ts[256];
  const int tid = threadIdx.x;
  int v0 = 0, v1 = 0;
  const int c0 = tid * 2;
  if (c0 < NC) v0 = ghist[c0 * NB + b];
  if (c0 + 1 < NC) v1 = ghist[(c0 + 1) * NB + b];
  ts[tid] = v0 + v1;
  __syncthreads();
  for (int o = 1; o < 256; o <<= 1) {
    const int x = (tid >= o) ? ts[tid - o] : 0;
    __syncthreads();
    ts[tid] += x;
    __syncthreads();
  }
  int run = (tid == 0) ? 0 : ts[tid - 1];
  if (c0 < NC) { gcur[b * NC + c0] = run; run += v0; }
  if (c0 + 1 < NC) gcur[b * NC + c0 + 1] = run;
  if (tid == 255) totals[b] = ts[255];
}

// k_mid: blocks 0..53 = pack, 54.. = bucketscan
__global__ __launch_bounds__(256) void k_mid(KPack KJ, const void* xdet,
    const int* __restrict__ ghist, int* __restrict__ gcur, int* __restrict__ totals) {
  if (blockIdx.x < 54) {
    const int isbf = detect_isbf(xdet);
    pack_dev(KJ, blockIdx.x, isbf);
  } else {
    bucketscan_dev(ghist, gcur, totals, blockIdx.x - 54);
  }
}

// ---------------------------------------------------------------------------
// base prefix over the 590 bucket totals, recomputed in LDS (tiny)
// ---------------------------------------------------------------------------
__device__ void base_from_totals(const int* __restrict__ totals, int* bsh) {
  __shared__ int ts[256];
  const int tid = threadIdx.x;
  const int i0 = tid * 3;
  int v0 = 0, v1 = 0, v2 = 0;
  if (i0 < NB) v0 = totals[i0];
  if (i0 + 1 < NB) v1 = totals[i0 + 1];
  if (i0 + 2 < NB) v2 = totals[i0 + 2];
  ts[tid] = v0 + v1 + v2;
  __syncthreads();
  for (int o = 1; o < 256; o <<= 1) {
    const int x = (tid >= o) ? ts[tid - o] : 0;
    __syncthreads();
    ts[tid] += x;
    __syncthreads();
  }
  int run = (tid == 0) ? 0 : ts[tid - 1];
  if (i0 < NB) { bsh[i0] = run; run += v0; }
  if (i0 + 1 < NB) { bsh[i0 + 1] = run; run += v1; }
  if (i0 + 2 < NB) bsh[i0 + 2] = run;
  if (tid == 0) bsh[NB] = ETOT;
  __syncthreads();
}

// ---------------------------------------------------------------------------
// bin: scatter (dst&255 | src) into bucket-ordered runs (LDS cursors)
// ---------------------------------------------------------------------------
__global__ __launch_bounds__(256) void k_bin(EJobs J,
    const int* __restrict__ gcur, const int* __restrict__ totals,
    unsigned int* __restrict__ bin) {
  __shared__ int bsh[NB + 1];
  __shared__ int cur[NB];
  base_from_totals(totals, bsh);
  const int c = blockIdx.x, tid = threadIdx.x;
  for (int i = tid; i < NB; i += 256) cur[i] = bsh[i] + gcur[i * NC + c];
  __syncthreads();
  const int e0 = c * CHUNK;
  #pragma unroll 4
  for (int t = 0; t < 36; ++t) {
    const int e = e0 + t * 256 + tid;
    if (e < ETOT) {
      const int j = e_job(e);
      const int le = e - e_base(j);
      const int d = J.dst[j][le];
      const int s = J.src[j][le];
      const int pos = atomicAdd(&cur[j * NBR + (d >> 8)], 1);
      bin[pos] = ((unsigned int)(d & 255) << 16) | (unsigned int)s;
    }
  }
}

// ---------------------------------------------------------------------------
// fill2: per bucket, sort 256 dsts in LDS, emit u16 CSR + offsets
// ---------------------------------------------------------------------------
__device__ void fill2_dev(const unsigned int* __restrict__ bin,
    const int* __restrict__ totals, u16* __restrict__ csr,
    int* __restrict__ offsets, int b) {
  __shared__ int bsh2[NB + 1];
  __shared__ int cnt[256], curs[256];
  base_from_totals(totals, bsh2);
  const int tid = threadIdx.x;
  const int rel = b / NBR;
  const int bloc = b - rel * NBR;
  const int d0 = bloc << 8;
  const int gbeg = bsh2[b];
  const int n = bsh2[b + 1] - gbeg;
  cnt[tid] = 0;
  __syncthreads();
  for (int i = tid; i < n; i += 256)
    atomicAdd(&cnt[bin[gbeg + i] >> 16], 1);
  __syncthreads();
  const int orig = cnt[tid];
  for (int o = 1; o < 256; o <<= 1) {
    const int x = (tid >= o) ? cnt[tid - o] : 0;
    __syncthreads();
    cnt[tid] += x;
    __syncthreads();
  }
  const int ex = cnt[tid] - orig;
  curs[tid] = ex;
  const int ebr = e_base(rel);
  const int d = d0 + tid;
  if (d < 30000) offsets[rel * CSTRIDE + d] = (gbeg - ebr) + ex;
  if (bloc == NBR - 1 && tid == 0)
    offsets[rel * CSTRIDE + 30000] = e_base(rel + 1) - ebr;
  __syncthreads();
  for (int i = tid; i < n; i += 256) {
    const unsigned int v = bin[gbeg + i];
    const int pos = atomicAdd(&curs[v >> 16], 1);
    csr[gbeg + pos] = (u16)(v & 0xffffu);
  }
}

// ---------------------------------------------------------------------------
// MFMA transform (R6/R9-proven): [Nx128]@[128x144]; tiles 0..7->z, 8->el/er
// ---------------------------------------------------------------------------
struct XJobs {
  const void* x[8]; const u16* bp[8]; u16* z[8]; float* el[8]; float* er[8];
  int N[8]; int t0[8]; int blk0[9];
};
__device__ void xform_dev(const XJobs& J, int xb, int isbf) {
  __shared__ __align__(16) u16 Bf[18432];
  __shared__ __align__(16) u16 As[64 * 136];
  const int tid = threadIdx.x;
  int job = 0;
  while (xb >= J.blk0[job + 1]) ++job;
  const int row0 = (xb - J.blk0[job]) * 64;
  const int N = J.N[job];
  const int t0 = J.t0[job];
  const u16* bp = J.bp[job];
  const void* x = J.x[job];

  if (t0 == 0) {
    for (int i = tid * 8; i < 18432; i += 2048)
      *(uint4*)&Bf[i] = *(const uint4*)&bp[i];
  } else {
    const int i = tid * 8;
    const int kc = i >> 9;
    const int off = (kc * 144 + 128) * 32 + (i & 511);
    *(uint4*)&Bf[off] = *(const uint4*)&bp[off];
  }

  if (isbf) {
    const uint4* xv = (const uint4*)x;
    for (int i = tid; i < 1024; i += 256) {
      const int r = i >> 4, c8 = i & 15;
      const int row = row0 + r;
      uint4 v = make_uint4(0, 0, 0, 0);
      if (row < N) v = xv[row * 16 + c8];
      *(uint4*)&As[r * 136 + c8 * 8] = v;
    }
  } else {
    const float4* xf = (const float4*)x;
    for (int i = tid; i < 2048; i += 256) {
      const int r = i >> 5, c4 = i & 31;
      const int row = row0 + r;
      unsigned long long pkv = 0ull;
      if (row < N) {
        const float4 v = xf[row * 32 + c4];
        pkv = (unsigned long long)f2bf(v.x) | ((unsigned long long)f2bf(v.y) << 16)
            | ((unsigned long long)f2bf(v.z) << 32) | ((unsigned long long)f2bf(v.w) << 48);
      }
      *(unsigned long long*)&As[r * 136 + c4 * 4] = pkv;
    }
  }
  __syncthreads();

  const int wave = tid >> 6;
  const int lane = tid & 63;
  const int q = lane >> 4;
  const int c = lane & 15;

  f32x4 accT[8];
  f32x4 acc8 = (f32x4){0.f, 0.f, 0.f, 0.f};
  if (t0 == 0) {
    #pragma unroll
    for (int t = 0; t < 8; ++t) accT[t] = (f32x4){0.f, 0.f, 0.f, 0.f};
  }

  #pragma unroll
  for (int kc = 0; kc < 4; ++kc) {
    const short8 a = *(const short8*)&As[(wave * 16 + c) * 136 + kc * 32 + q * 8];
    if (t0 == 0) {
      #pragma unroll
      for (int t = 0; t < 8; ++t) {
        const short8 bb = *(const short8*)&Bf[((kc * 144 + t * 16 + c) * 4 + q) * 8];
        accT[t] = __builtin_amdgcn_mfma_f32_16x16x32_bf16(a, bb, accT[t], 0, 0, 0);
      }
    }
    const short8 b8 = *(const short8*)&Bf[((kc * 144 + 128 + c) * 4 + q) * 8];
    acc8 = __builtin_amdgcn_mfma_f32_16x16x32_bf16(a, b8, acc8, 0, 0, 0);
  }

  const int rbase = row0 + wave * 16 + q * 4;
  if (t0 == 0 && J.z[job]) {
    u16* zo = J.z[job];
    #pragma unroll
    for (int t = 0; t < 8; ++t)
      #pragma unroll
      for (int r = 0; r < 4; ++r) {
        const int row = rbase + r;
        if (row < N) zo[row * 128 + t * 16 + c] = f2bf(accT[t][r]);
      }
  }
  #pragma unroll
  for (int r = 0; r < 4; ++r) {
    const int row = rbase + r;
    if (row < N) {
      const float v = acc8[r];
      if (c < 8) { if (J.el[job]) J.el[job][row * 8 + c] = v; }
      else       { if (J.er[job]) J.er[job][row * 8 + (c - 8)] = v; }
    }
  }
}

// k_l4: blocks 0..589 = fill2, 590.. = xform
__global__ __launch_bounds__(256) void k_l4(XJobs XJ, const void* xdet,
    const unsigned int* __restrict__ bin, const int* __restrict__ totals,
    u16* __restrict__ csr, int* __restrict__ offsets) {
  if (blockIdx.x < NB) {
    fill2_dev(bin, totals, csr, offsets, blockIdx.x);
  } else {
    const int isbf = detect_isbf(xdet);
    xform_dev(XJ, blockIdx.x - NB, isbf);
  }
}

// ---------------------------------------------------------------------------
// Aggregation: one wave per (relation, dst). 16 edges/window for 2x MLP:
// lane (h,i) computes ex for edges p+i and p+8+i; 16 readlanes; 16 z loads
// issued back-to-back; two 8-edge consume phases (bpermute + FMA).
// ---------------------------------------------------------------------------
struct AJobs { const u16* csr[5]; const int* off[5]; const float* el[5];
               const float* er[5]; const u16* z[5]; const void* b[5];
               u16* feats[5]; int stride[5]; };
__global__ __launch_bounds__(256) void k_agg_all(AJobs J, const void* xdet) {
  const int isbf = detect_isbf(xdet);
  const int gw = (blockIdx.x * 256 + threadIdx.x) >> 6;
  const int lane = threadIdx.x & 63;
  const int job = gw / 30000;
  const int d = gw - job * 30000;
  const int h = lane >> 3;            // head of this lane's feature pair
  const int i8 = lane & 7;            // which of 8 edges this lane exps
  const float* el = J.el[job];
  const u16* ztl = J.z[job] + lane * 2;   // per-lane z base
  const u16* csr = J.csr[job];
  const float erh = J.er[job][d * 8 + h];
  const int beg = J.off[job][d];
  const int end = J.off[job][d + 1];
  const int gb4 = (lane & 56) << 2;   // bpermute byte base of this h-group

  float a0 = 0.f, a1 = 0.f, denP = 0.f;
  for (int p = beg; p < end; p += 16) {
    const int iA = p + i8;
    const int iB = p + 8 + i8;
    const int sA = (int)csr[iA < end ? iA : (end - 1)];
    const int sB = (int)csr[iB < end ? iB : (end - 1)];
    float ehA = el[sA * 8 + h] + erh;
    float ehB = el[sB * 8 + h] + erh;
    ehA = fminf(fmaxf(ehA, 0.2f * ehA), 60.f);   // leaky_relu + clamp
    ehB = fminf(fmaxf(ehB, 0.2f * ehB), 60.f);
    const float exA = (iA < end) ? __expf(ehA) : 0.f;
    const float exB = (iB < end) ? __expf(ehB) : 0.f;
    denP += exA + exB;
    int si[16];
    #pragma unroll
    for (int i = 0; i < 8; ++i) si[i] = __builtin_amdgcn_readlane(sA, i);
    #pragma unroll
    for (int i = 0; i < 8; ++i) si[8 + i] = __builtin_amdgcn_readlane(sB, i);
    unsigned int zp[16];
    #pragma unroll
    for (int i = 0; i < 16; ++i)
      zp[i] = *(const unsigned int*)(ztl + si[i] * 128);
    const int exbA = __float_as_int(exA);
    const int exbB = __float_as_int(exB);
    #pragma unroll
    for (int i = 0; i < 8; ++i) {
      const float exi = __int_as_float(
          __builtin_amdgcn_ds_bpermute(gb4 + i * 4, exbA));
      union { unsigned int u; float f; } lo, hi;
      lo.u = zp[i] << 16; hi.u = zp[i] & 0xffff0000u;
      a0 = fmaf(exi, lo.f, a0);
      a1 = fmaf(exi, hi.f, a1);
    }
    #pragma unroll
    for (int i = 0; i < 8; ++i) {
      const float exi = __int_as_float(
          __builtin_amdgcn_ds_bpermute(gb4 + i * 4, exbB));
      union { unsigned int u; float f; } lo, hi;
      lo.u = zp[8 + i] << 16; hi.u = zp[8 + i] & 0xffff0000u;
      a0 = fmaf(exi, lo.f, a0);
      a1 = fmaf(exi, hi.f, a1);
    }
  }
  denP += __shfl_xor(denP, 1);
  denP += __shfl_xor(denP, 2);
  denP += __shfl_xor(denP, 4);        // full den(h) within the 8-lane group
  const float inv = 1.f / fmaxf(denP, 1e-9f);
  const int j0 = lane * 2;
  const float v0 = a0 * inv + ld_in(J.b[job], j0, isbf);
  const float v1 = a1 * inv + ld_in(J.b[job], j0 + 1, isbf);
  const unsigned int packed = (unsigned int)f2bf(v0) | ((unsigned int)f2bf(v1) << 16);
  *(unsigned int*)(J.feats[job] + d * J.stride[job] + j0) = packed;
}

// ---------------------------------------------------------------------------
// Fused semantic score + combine (R11-proven). Node-aligned M-tiles; scores
// -> LDS; per-node softmax (b2 drops out); combine from the As LDS tile.
// ---------------------------------------------------------------------------
__global__ __launch_bounds__(256) void k_semco(
    const u16* __restrict__ f, const u16* __restrict__ w1pack,
    const void* __restrict__ b1, const void* __restrict__ W2,
    void* __restrict__ out, const void* xdet)
{
  __shared__ __align__(16) u16 Bf[18432];
  __shared__ __align__(16) u16 As[64 * 136];
  __shared__ float b1S[128], W2S[128];
  __shared__ float sS[64];
  __shared__ float wS[128];
  const int isbf = detect_isbf(xdet);
  const int tid = threadIdx.x;
  const bool drug = (blockIdx.x < NBD);
  const int bloc = drug ? blockIdx.x : blockIdx.x - NBD;
  const int row0 = drug ? bloc * 63 : 90000 + bloc * 64;
  const int rowLim = drug ? 90000 : 150000;

  for (int i = tid * 8; i < 18432; i += 2048)
    *(uint4*)&Bf[i] = *(const uint4*)&w1pack[i];
  if (tid < 128) { b1S[tid] = ld_in(b1, tid, isbf); W2S[tid] = ld_in(W2, tid, isbf); }
  {
    const uint4* xv = (const uint4*)f;
    for (int i = tid; i < 1024; i += 256) {
      const int r = i >> 4, c8 = i & 15;
      const int row = row0 + r;
      uint4 v = make_uint4(0, 0, 0, 0);
      if (row < rowLim) v = xv[row * 16 + c8];
      *(uint4*)&As[r * 136 + c8 * 8] = v;
    }
  }
  __syncthreads();

  const int wave = tid >> 6;
  const int lane = tid & 63;
  const int q = lane >> 4;
  const int c = lane & 15;

  f32x4 acc[8];
  #pragma unroll
  for (int t = 0; t < 8; ++t) acc[t] = (f32x4){0.f, 0.f, 0.f, 0.f};

  #pragma unroll
  for (int kc = 0; kc < 4; ++kc) {
    const short8 a = *(const short8*)&As[(wave * 16 + c) * 136 + kc * 32 + q * 8];
    #pragma unroll
    for (int t = 0; t < 8; ++t) {
      const short8 bb = *(const short8*)&Bf[((kc * 144 + t * 16 + c) * 4 + q) * 8];
      acc[t] = __builtin_amdgcn_mfma_f32_16x16x32_bf16(a, bb, acc[t], 0, 0, 0);
    }
  }

  float part[4] = {0.f, 0.f, 0.f, 0.f};
  #pragma unroll
  for (int t = 0; t < 8; ++t) {
    const int n = t * 16 + c;
    const float b1v = b1S[n];
    const float w2v = W2S[n];
    #pragma unroll
    for (int r = 0; r < 4; ++r) {
      const float hv = acc[t][r] + b1v;
      const float e = __expf(2.f * hv);
      const float th = 1.f - 2.f / (e + 1.f);   // tanh, overflow-safe
      part[r] = fmaf(th, w2v, part[r]);
    }
  }
  #pragma unroll
  for (int r = 0; r < 4; ++r) {
    part[r] += __shfl_xor(part[r], 1);
    part[r] += __shfl_xor(part[r], 2);
    part[r] += __shfl_xor(part[r], 4);
    part[r] += __shfl_xor(part[r], 8);
  }
  if (c == 0) {
    #pragma unroll
    for (int r = 0; r < 4; ++r)
      sS[wave * 16 + q * 4 + r] = part[r];      // b2 omitted: softmax-invariant
  }
  __syncthreads();

  // ---- per-node softmax over relation scores ----
  const int R = drug ? 3 : 2;
  const int nmax = drug ? 21 : 32;
  int nnode = 30000 - bloc * nmax;
  if (nnode > nmax) nnode = nmax;
  if (tid < nnode) {
    const float s0v = sS[tid * R];
    const float s1v = sS[tid * R + 1];
    const float s2v = (R == 3) ? sS[tid * R + 2] : -3.4e38f;
    const float mx = fmaxf(fmaxf(s0v, s1v), s2v);
    const float w0 = __expf(s0v - mx);
    const float w1 = __expf(s1v - mx);
    const float w2 = (R == 3) ? __expf(s2v - mx) : 0.f;
    const float inv = 1.f / (w0 + w1 + w2);
    wS[tid * 4 + 0] = w0 * inv;
    wS[tid * 4 + 1] = w1 * inv;
    wS[tid * 4 + 2] = w2 * inv;
  }
  __syncthreads();

  // ---- combine from the As tile (feats already in LDS) ----
  const int node0 = bloc * nmax;
  const int tot = nnode * 64;                   // u32-pair outputs
  for (int idx = tid; idx < tot; idx += 256) {
    const int node = idx >> 6;
    const int j2 = idx & 63;
    const int lr = node * R;
    const float w0 = wS[node * 4], w1 = wS[node * 4 + 1], w2 = wS[node * 4 + 2];
    const unsigned int f0 = *(const unsigned int*)&As[lr * 136 + j2 * 2];
    const unsigned int f1 = *(const unsigned int*)&As[(lr + 1) * 136 + j2 * 2];
    union { unsigned int u; float ff; } t;
    float acc0, acc1;
    t.u = f0 << 16;          acc0 = w0 * t.ff;
    t.u = f0 & 0xffff0000u;  acc1 = w0 * t.ff;
    t.u = f1 << 16;          acc0 = fmaf(w1, t.ff, acc0);
    t.u = f1 & 0xffff0000u;  acc1 = fmaf(w1, t.ff, acc1);
    if (drug) {
      const unsigned int f2v = *(const unsigned int*)&As[(lr + 2) * 136 + j2 * 2];
      t.u = f2v << 16;         acc0 = fmaf(w2, t.ff, acc0);
      t.u = f2v & 0xffff0000u; acc1 = fmaf(w2, t.ff, acc1);
    }
    const int oi = (drug ? 0 : 1920000) + (node0 + node) * 64 + j2;
    if (isbf) {
      ((unsigned int*)out)[oi] =
          (unsigned int)f2bf(acc0) | ((unsigned int)f2bf(acc1) << 16);
    } else {
      float2 v; v.x = acc0; v.y = acc1;
      ((float2*)out)[oi] = v;
    }
  }
}

extern "C" void kernel_launch(void* const* d_in, const int* in_sizes, int n_in,
                              void* d_out, int out_size, void* d_ws, size_t ws_size,
                              hipStream_t stream)
{
  (void)in_sizes; (void)n_in; (void)out_size; (void)ws_size;

  const void* h_drug = d_in[0];
  const void* h_prot = d_in[1];
  const void* h_se   = d_in[2];
  const void* W_dd = d_in[3];  const void* al_dd = d_in[4];
  const void* ar_dd = d_in[5]; const void* b_dd  = d_in[6];
  const void* W_dp = d_in[7];  const void* al_dp = d_in[8];
  const void* ar_dp = d_in[9]; const void* b_dp  = d_in[10];
  const void* W_pd = d_in[11]; const void* al_pd = d_in[12];
  const void* ar_pd = d_in[13];const void* b_pd  = d_in[14];
  const void* W_pp = d_in[15]; const void* al_pp = d_in[16];
  const void* ar_pp = d_in[17];const void* b_pp  = d_in[18];
  const void* W_sd = d_in[19]; const void* al_sd = d_in[20];
  const void* ar_sd = d_in[21];const void* b_sd  = d_in[22];
  const void* W1 = d_in[23];   const void* b1 = d_in[24];
  const void* W2 = d_in[25];   const void* b2 = d_in[26];
  (void)b2;  // cancels in relation softmax (shift invariance)
  const int* src_dd = (const int*)d_in[27];
  const int* dst_dd = (const int*)d_in[28];
  const int* src_dp = (const int*)d_in[29];
  const int* dst_dp = (const int*)d_in[30];
  const int* src_pd = (const int*)d_in[31];
  const int* dst_pd = (const int*)d_in[32];
  const int* src_pp = (const int*)d_in[33];
  const int* dst_pp = (const int*)d_in[34];
  const int* src_sd = (const int*)d_in[35];
  const int* dst_sd = (const int*)d_in[36];

  // ---- workspace layout (~94.1 MB <= 101.4 MB proven in R6) ----
  char* w = (char*)d_ws;
  float* el5   = (float*)(w);                    // 4,800,000
  float* er5   = (float*)(w + 4800000);          // 4,800,000
  u16* z_dd    = (u16*)(w + 9600000);            // 7,680,000
  u16* z_pd    = (u16*)(w + 17280000);           // 7,680,000
  u16* z_sd    = (u16*)(w + 24960000);           // 2,560,000
  u16* z_dp    = (u16*)(w + 27520000);           // 7,680,000
  u16* z_pp    = (u16*)(w + 35200000);           // 7,680,000
  int* offsets = (int*)(w + 42880000);           // 600,320
  u16* csr     = (u16*)(w + 43480320);           // 9,000,000
  int* ghist   = (int*)(w + 52480320);           // 1,154,040
  int* gcur    = (int*)(w + 53634560);           // 1,154,040
  int* totals  = (int*)(w + 54788608);           // 2,360
  u16* feats   = (u16*)(w + 55391232);           // 38,400,000 (16B aligned)
  unsigned int* bin = (unsigned int*)(w + 55391232); // aliases feats (dead before agg)
  float* ww    = (float*)(w + 93791232);         // 40,960 (wal/war x5)
  u16* packs   = (u16*)(w + 93832192);           // 221,184 -> end 94,053,376

  float *wal[5], *war[5];
  for (int r = 0; r < 5; ++r) { wal[r] = ww + r * 2048; war[r] = ww + r * 2048 + 1024; }
  u16* pk[6];
  for (int r = 0; r < 6; ++r) pk[r] = packs + r * 18432;
  float* el_r[5]; float* er_r[5];
  for (int r = 0; r < 5; ++r) { el_r[r] = el5 + r * 240000; er_r[r] = er5 + r * 240000; }
  u16* feats_d = feats;               // drug: 30000 x 384
  u16* feats_p = feats + 11520000;    // prot: 30000 x 256

  const dim3 blk(256);

  // rel order: 0=dd 1=pd 2=sd 3=dp 4=pp
  PJobs pj;
  pj.W[0]=W_dd; pj.al[0]=al_dd; pj.ar[0]=ar_dd;
  pj.W[1]=W_pd; pj.al[1]=al_pd; pj.ar[1]=ar_pd;
  pj.W[2]=W_sd; pj.al[2]=al_sd; pj.ar[2]=ar_sd;
  pj.W[3]=W_dp; pj.al[3]=al_dp; pj.ar[3]=ar_dp;
  pj.W[4]=W_pp; pj.al[4]=al_pp; pj.ar[4]=ar_pp;
  for (int r = 0; r < 5; ++r) { pj.wal[r] = wal[r]; pj.war[r] = war[r]; }

  EJobs ej;
  ej.src[0]=src_dd; ej.dst[0]=dst_dd;
  ej.src[1]=src_pd; ej.dst[1]=dst_pd;
  ej.src[2]=src_sd; ej.dst[2]=dst_sd;
  ej.src[3]=src_dp; ej.dst[3]=dst_dp;
  ej.src[4]=src_pp; ej.dst[4]=dst_pp;

  KPack kp;
  kp.W[0]=W_dd; kp.W[1]=W_pd; kp.W[2]=W_sd; kp.W[3]=W_dp; kp.W[4]=W_pp; kp.W[5]=W1;
  for (int r = 0; r < 5; ++r) { kp.wal[r] = wal[r]; kp.war[r] = war[r]; }
  kp.wal[5]=nullptr; kp.war[5]=nullptr;
  for (int r = 0; r < 6; ++r) kp.out[r] = pk[r];

  XJobs xj;
  auto setx = [&](int i, const void* x, const u16* bp, u16* z, float* el,
                  float* er, int N, int t0) {
    xj.x[i]=x; xj.bp[i]=bp; xj.z[i]=z; xj.el[i]=el; xj.er[i]=er; xj.N[i]=N; xj.t0[i]=t0;
  };
  setx(0, h_drug, pk[0], z_dd, el_r[0], er_r[0], ND, 0);   // dd
  setx(1, h_prot, pk[1], z_pd, el_r[1], nullptr, NP, 0);   // pd src
  setx(2, h_drug, pk[1], nullptr, nullptr, er_r[1], ND, 8);// pd dst
  setx(3, h_se,   pk[2], z_sd, el_r[2], nullptr, NS, 0);   // sd src
  setx(4, h_drug, pk[2], nullptr, nullptr, er_r[2], ND, 8);// sd dst
  setx(5, h_drug, pk[3], z_dp, el_r[3], nullptr, ND, 0);   // dp src
  setx(6, h_prot, pk[3], nullptr, nullptr, er_r[3], NP, 8);// dp dst
  setx(7, h_prot, pk[4], z_pp, el_r[4], er_r[4], NP, 0);   // pp
  int xblocks = 0;
  for (int i = 0; i < 8; ++i) { xj.blk0[i] = xblocks; xblocks += (xj.N[i] + 63) / 64; }
  xj.blk0[8] = xblocks;

  AJobs aj;
  const int ebase[5] = {0, 1000000, 2000000, 2500000, 3500000};
  const void* bias[5] = {b_dd, b_pd, b_sd, b_dp, b_pp};
  u16* fb[5] = {feats_d, feats_d + 128, feats_d + 256, feats_p, feats_p + 128};
  const int fstride[5] = {384, 384, 384, 256, 256};
  const u16* zz[5] = {z_dd, z_pd, z_sd, z_dp, z_pp};
  for (int r = 0; r < 5; ++r) {
    aj.csr[r] = csr + ebase[r];
    aj.off[r] = offsets + r * CSTRIDE;
    aj.el[r] = el_r[r];
    aj.er[r] = er_r[r];
    aj.z[r] = zz[r];
    aj.b[r] = bias[r];
    aj.feats[r] = fb[r];
    aj.stride[r] = fstride[r];
  }

  // ---- 6 launches, no memsets ----
  k_front<<<dim3(5 + NC), blk, 0, stream>>>(pj, ej, h_drug, ghist);
  k_mid<<<dim3(54 + NB), blk, 0, stream>>>(kp, h_drug, ghist, gcur, totals);
  k_bin<<<dim3(NC), blk, 0, stream>>>(ej, gcur, totals, bin);
  k_l4<<<dim3(NB + xblocks), blk, 0, stream>>>(xj, h_drug, bin, totals, csr, offsets);
  k_agg_all<<<dim3(37500), blk, 0, stream>>>(aj, h_drug);
  k_semco<<<dim3(NBD + NBP), blk, 0, stream>>>(feats, pk[5], b1, W2, d_out, h_drug);
}